// Round 9
// baseline (292.601 us; speedup 1.0000x reference)
//
#include <hip/hip_runtime.h>

typedef _Float16 half8 __attribute__((ext_vector_type(8)));
typedef float f32x4  __attribute__((ext_vector_type(4)));
typedef float f32x16 __attribute__((ext_vector_type(16)));

#define NRAYS 2048
#define SAMP 84
#define NPTS (NRAYS*SAMP)   // 172032
#define SEMSTR 52           // padded sem row stride (halves)

// ---- half-element offsets inside the weight region ----
// pack: [frag F(32 cols)][kt(K16)][lane l(64)][h(8 halves)] ;
//   n = F*32 + (l&31), k = kt*16 + (l>>5)*8 + h
#define WT0_OFF   0         // 8 frags x KT4
#define WTH_OFF   16384     // 6 x (8 frags x KT16)
#define WTS_OFF   409600    // 8 frags x KT20
#define WTHD_OFF  491520    // 10 frags x KT16
#define WTR1_OFF  573440    // 4 frags x KT18
#define WTR2_OFF  610304    // 1 frag x KT8
#define WT_TOTAL  614400
#define NBIAS     2512

// ---- ws byte offsets ----
#define OFF_WT    ((size_t)0)
#define OFF_BIAS  ((size_t)1228800)                 // WT_TOTAL*2
#define OFF_Z     (OFF_BIAS + (size_t)NBIAS*4)
#define OFF_SCALE (OFF_Z + (size_t)NPTS*4)
#define OFF_SIGMA (OFF_SCALE + (size_t)NRAYS*4)
#define OFF_RGB   (OFF_SIGMA + (size_t)NPTS*4)
#define OFF_SEM   (OFF_RGB + (size_t)NPTS*12)

// ============================================================== prep
__global__ __launch_bounds__(256) void prep_kernel(
    const float* __restrict__ w_in,  const float* __restrict__ w_h,
    const float* __restrict__ w_skip,const float* __restrict__ w_sigma,
    const float* __restrict__ w_feat,const float* __restrict__ w_rgb1,
    const float* __restrict__ w_rgb2,const float* __restrict__ w_sem,
    const float* __restrict__ b_in,  const float* __restrict__ b_h,
    const float* __restrict__ b_skip,const float* __restrict__ b_sigma,
    const float* __restrict__ b_feat,const float* __restrict__ b_rgb1,
    const float* __restrict__ b_rgb2,const float* __restrict__ b_sem,
    _Float16* __restrict__ wt, float* __restrict__ bias)
{
  int idx = blockIdx.x*256 + threadIdx.x;
  if (idx < WT_TOTAL) {
    float v; int n, k, l, h, kt, F, rem;
    if (idx < WTH_OFF) {                 // L0: 8 frags x KT4 (2048/frag)
      F = idx >> 11; rem = idx & 2047; kt = rem >> 9; int q = rem & 511;
      l = q >> 3; h = q & 7;
      n = F*32 + (l&31); k = kt*16 + ((l>>5)<<3) + h;
      v = (k < 63) ? w_in[k*256 + n] : 0.f;
    } else if (idx < WTS_OFF) {          // hidden: 6 x (8 frags x KT16)
      int r = idx - WTH_OFF; int i = r >> 16; int rr = r & 65535;
      F = rr >> 13; rem = rr & 8191; kt = rem >> 9; int q = rem & 511;
      l = q >> 3; h = q & 7;
      n = F*32 + (l&31); k = kt*16 + ((l>>5)<<3) + h;
      v = w_h[(i<<16) + (k<<8) + n];
    } else if (idx < WTHD_OFF) {         // skip: 8 frags x KT20 (10240/frag)
      int r = idx - WTS_OFF;
      F = r / 10240; rem = r % 10240; kt = rem >> 9; int q = rem & 511;
      l = q >> 3; h = q & 7;
      n = F*32 + (l&31); k = kt*16 + ((l>>5)<<3) + h;
      v = (k < 319) ? w_skip[k*256 + n] : 0.f;
    } else if (idx < WTR1_OFF) {         // head: 10 frags x KT16
      int r = idx - WTHD_OFF;
      F = r >> 13; rem = r & 8191; kt = rem >> 9; int q = rem & 511;
      l = q >> 3; h = q & 7;
      n = F*32 + (l&31); k = kt*16 + ((l>>5)<<3) + h;
      v = (n < 256) ? w_feat[(k<<8) + n]
        : (n < 306) ? w_sem[k*50 + (n-256)]
        : (n == 306)? w_sigma[k] : 0.f;
    } else if (idx < WTR2_OFF) {         // rgb1: 4 frags x KT18 (9216/frag)
      int r = idx - WTR1_OFF;
      F = r / 9216; rem = r % 9216; kt = rem >> 9; int q = rem & 511;
      l = q >> 3; h = q & 7;
      n = F*32 + (l&31); k = kt*16 + ((l>>5)<<3) + h;
      v = (k < 283) ? w_rgb1[k*128 + n] : 0.f;
    } else {                             // rgb2: 1 frag x KT8
      int r = idx - WTR2_OFF;
      kt = r >> 9; int q = r & 511;
      l = q >> 3; h = q & 7;
      n = (l&31); k = kt*16 + ((l>>5)<<3) + h;
      v = (n < 3) ? w_rgb2[k*3 + n] : 0.f;
    }
    wt[idx] = (_Float16)v;
  } else if (idx < WT_TOTAL + NBIAS) {
    int j = idx - WT_TOTAL; float v;
    if (j < 2048) {
      int i = j >> 8, c = j & 255;
      v = (i==0) ? b_in[c] : (i<4) ? b_h[(i-1)*256+c]
        : (i==4) ? b_skip[c] : b_h[(i-2)*256+c];
    } else if (j < 2368) {
      int c = j - 2048;
      v = (c<256) ? b_feat[c] : (c<306) ? b_sem[c-256]
        : (c==306) ? b_sigma[0] : 0.f;
    } else if (j < 2496) v = b_rgb1[j-2368];
    else { int c = j-2496; v = (c<3) ? b_rgb2[c] : 0.f; }
    bias[j] = v;
  }
}

// ============================================================== sampling
__global__ __launch_bounds__(256) void sample_kernel(
    const float* __restrict__ rays, const float* __restrict__ inter,
    const float* __restrict__ noise, float* __restrict__ zbuf,
    float* __restrict__ scaleb)
{
  __shared__ float sv[240], ss[240], z2[84];
  const int ray = blockIdx.x, t = threadIdx.x;
  const float* bx = inter + (size_t)ray*40;
  if (t < 240) {
    int b = t/24, j = t%24;
    float nr = bx[b*4], fr = bx[b*4+1];
    float tj = (j==23) ? 1.f : (float)j * (1.f/23.f);
    sv[t] = nr + (fr-nr)*tj;
  }
  __syncthreads();
  if (t < 240) {
    float v = sv[t]; int r = 0;
    for (int i = 0; i < 240; ++i) { float vi = sv[i]; r += (vi < v) || (vi == v && i < t); }
    ss[r] = v;
  }
  __syncthreads();
  if (t < 64) {
    float z;
    if (t == 63) z = ss[239];
    else { int num = t*239; int k = num/63; float f = (float)(num - k*63)*(1.f/63.f);
           z = ss[k] + f*(ss[k+1]-ss[k]); }
    z2[t] = z;
  } else if (t < 84) {
    int b = t - 64;
    z2[t] = (b < 10) ? (bx[b*4] - 1e-5f) : (bx[(b-10)*4+1] + 1e-5f);
  }
  __syncthreads();
  if (t < 84) { float z = z2[t]; if (z < 0.f) z = 200.f + 20.f*noise[(size_t)ray*84 + t]; z2[t] = z; }
  __syncthreads();
  if (t < 84) {
    float v = z2[t]; int r = 0;
    for (int i = 0; i < 84; ++i) { float vi = z2[i]; r += (vi < v) || (vi == v && i < t); }
    zbuf[(size_t)ray*84 + r] = v;
  }
  if (t == 0) {
    float dx = rays[ray*6+3], dy = rays[ray*6+4], dz = rays[ray*6+5];
    scaleb[ray] = sqrtf(dx*dx + dy*dy + dz*dz);
  }
}

// ============================================================== MLP
// 64 pts/block, 256 threads = 4 waves, pure n-split. mfma_f32_32x32x16_f16.
// Per wave: NF=2 frags of 32 cols (64 cols), MF=2 row-tiles of 32 (all 64 rows).
// Single in-place buffer: [64 rows][320 cols] f16, stride 640B, 16B-chunk XOR
// swizzle. 40KB -> 3 blocks/CU (VGPR-limited). x_enc/d_enc live in cols 256+.
#define LDS_TOTAL 40960

__device__ __forceinline__ uint32_t laddr(int m, int k) {
  return (uint32_t)(m*640) + (uint32_t)((((k>>3)^(m&7))<<4) + ((k&7)<<1));
}
struct __attribute__((aligned(8))) H4 { _Float16 h[4]; };

__device__ __forceinline__ float xenc_val(int j, float x0, float x1, float x2) {
  if (j >= 63) return 0.f;
  if (j < 3) return j==0?x0:(j==1?x1:x2);
  int q = j-3, lf = q/6, r = q%6, ci = r%3;
  float xc = (ci==0)?x0:((ci==1)?x1:x2);
  float arg = xc * (float)(1<<lf);
  return (r<3) ? sinf(arg) : cosf(arg);
}
__device__ __forceinline__ float denc_val(int c, float u0, float u1, float u2) {
  if (c >= 27) return 0.f;
  if (c < 3) return c==0?u0:(c==1?u1:u2);
  int q = c-3, lf = q/6, r = q%6, ci = r%3;
  float uc = (ci==0)?u0:((ci==1)?u1:u2);
  float arg = uc * (float)(1<<lf);
  return (r<3) ? sinf(arg) : cosf(arg);
}

// 4 waves, wave wn: frags [fbase+wn*NF, +NF), rows 0..63 (MF=2 tiles of 32).
// KT = number of K16 steps. XOFF = column base of the K-input in buf.
// MODE 0: write f16 frags back to buf (opt RELU). MODE 1: sem/sigma -> global.
// INPLACE: __syncthreads() after the MFMA loop (all reads) before LDS writes.
// Weight ring depth DW=4, lead 3 (refill slot (kt+3)%4 != consume slot kt%4).
template<int KT, int NF, int MODE, bool RELU, int XOFF, bool INPLACE>
__device__ __forceinline__ void gemm(uint8_t* smem,
    const _Float16* __restrict__ WT, int fbase, const float* __restrict__ bias0,
    int p0, float* __restrict__ sigmaws, _Float16* __restrict__ semws)
{
  constexpr int MF = 2;
  const int t = threadIdx.x;
  const int l = t & 63, wn = t >> 6;
  const int lr = l & 31, lg = l >> 5;
  constexpr int DW   = (KT <= 3) ? KT : 4;
  constexpr int LEAD = (KT <= 3) ? KT : 3;
  f32x16 acc[NF][MF];
#pragma unroll
  for (int i = 0; i < NF; ++i)
#pragma unroll
    for (int j = 0; j < MF; ++j)
#pragma unroll
      for (int r = 0; r < 16; ++r) acc[i][j][r] = 0.f;
  const _Float16* wb = WT + (size_t)((fbase + wn*NF)*KT)*512 + (size_t)l*8;
  half8 av[DW][NF];
  half8 bv[2][MF];
  auto baddr = [&](int mf, int kt)->uint32_t {
    return laddr(mf*32 + lr, XOFF + kt*16 + lg*8);
  };
  // prologue: weights kt=0..LEAD-1, activations kt=0
#pragma unroll
  for (int d = 0; d < LEAD && d < KT; ++d)
#pragma unroll
    for (int nf = 0; nf < NF; ++nf)
      av[d][nf] = *(const half8*)(wb + (size_t)(nf*KT + d)*512);
#pragma unroll
  for (int mf = 0; mf < MF; ++mf)
    bv[0][mf] = *(const half8*)(smem + baddr(mf, 0));
#pragma unroll
  for (int kt = 0; kt < KT; ++kt) {
    if (kt + 1 < KT) {
#pragma unroll
      for (int mf = 0; mf < MF; ++mf)
        bv[(kt+1)&1][mf] = *(const half8*)(smem + baddr(mf, kt+1));
    }
    if (kt + LEAD < KT) {
#pragma unroll
      for (int nf = 0; nf < NF; ++nf)
        av[(kt+LEAD)%DW][nf] = *(const half8*)(wb + (size_t)(nf*KT + kt + LEAD)*512);
    }
    __builtin_amdgcn_sched_barrier(0);
#pragma unroll
    for (int nf = 0; nf < NF; ++nf)
#pragma unroll
      for (int mf = 0; mf < MF; ++mf)
        acc[nf][mf] = __builtin_amdgcn_mfma_f32_32x32x16_f16(
            av[kt%DW][nf], bv[kt&1][mf], acc[nf][mf], 0, 0, 0);
    __builtin_amdgcn_sched_barrier(0);
  }
  if (INPLACE) __syncthreads();   // all reads of buf done -> safe to overwrite
  // D layout (32x32): activation row m = mtile*32 + (lane&31);
  // weight col n = ncol0 + (r&3) + 8*(r>>2) + 4*(lane>>5), r in [0,16)
#pragma unroll
  for (int nf = 0; nf < NF; ++nf) {
    const int ncol0 = (fbase + wn*NF + nf)*32;
#pragma unroll
    for (int mf = 0; mf < MF; ++mf) {
      const int m = mf*32 + lr;
      const f32x16 v = acc[nf][mf];
#pragma unroll
      for (int g = 0; g < 4; ++g) {
        const int nst = ncol0 + 8*g + 4*lg;
        const f32x4 b4 = *(const f32x4*)(bias0 + nst);
        float x0 = v[4*g+0] + b4[0], x1 = v[4*g+1] + b4[1];
        float x2 = v[4*g+2] + b4[2], x3 = v[4*g+3] + b4[3];
        if (RELU) { x0 = fmaxf(x0,0.f); x1 = fmaxf(x1,0.f);
                    x2 = fmaxf(x2,0.f); x3 = fmaxf(x3,0.f); }
        if (MODE == 0) {
          H4 hh; hh.h[0]=(_Float16)x0; hh.h[1]=(_Float16)x1;
                 hh.h[2]=(_Float16)x2; hh.h[3]=(_Float16)x3;
          *(H4*)(smem + laddr(m, nst)) = hh;
        } else {
          const int cb = nst - 256;
          const int pp = p0 + m;
          if (cb <= 44) {
            H4 hh; hh.h[0]=(_Float16)x0; hh.h[1]=(_Float16)x1;
                   hh.h[2]=(_Float16)x2; hh.h[3]=(_Float16)x3;
            *(H4*)(semws + (size_t)pp*SEMSTR + cb) = hh;
          } else if (cb == 48) {
            semws[(size_t)pp*SEMSTR + 48] = (_Float16)x0;
            semws[(size_t)pp*SEMSTR + 49] = (_Float16)x1;
            sigmaws[pp] = x2;
          }
        }
      }
    }
  }
}

__device__ __forceinline__ void gemm_rgb2(uint8_t* smem,
    const _Float16* __restrict__ WT, const float* __restrict__ bias,
    int p0, float* __restrict__ rgbws)
{
  const int t = threadIdx.x;
  const int l = t & 63, w = t >> 6;
  if (w >= 2) return;                   // 2 waves x 32 rows = 64 pts
  const int lr = l & 31, lg = l >> 5;
  f32x16 acc;
#pragma unroll
  for (int r = 0; r < 16; ++r) acc[r] = 0.f;
  const _Float16* wb = WT + (size_t)l*8;
#pragma unroll
  for (int kt = 0; kt < 8; ++kt) {
    half8 a = *(const half8*)(wb + (size_t)kt*512);
    half8 b = *(const half8*)(smem + laddr(w*32 + lr, kt*16 + lg*8));
    acc = __builtin_amdgcn_mfma_f32_32x32x16_f16(a, b, acc, 0, 0, 0);
  }
  if (lg == 0) {                        // n = r for r<4 when lane>>5 == 0
    const int pp = p0 + w*32 + lr;
#pragma unroll
    for (int r = 0; r < 3; ++r)
      rgbws[(size_t)pp*3 + r] = acc[r] + bias[r];
  }
}

__global__ __launch_bounds__(256,3) void mlp_kernel(
    const float* __restrict__ rays, const float* __restrict__ zbuf,
    const float* __restrict__ scaleb, const _Float16* __restrict__ wt,
    const float* __restrict__ bias, float* __restrict__ sigmaws,
    float* __restrict__ rgbws, _Float16* __restrict__ semws)
{
  extern __shared__ uint8_t smem[];
  const int p0 = blockIdx.x*64;
  const int t = threadIdx.x;
  const int m = t & 63, g = t >> 6;    // 4 threads per row
  const int p = p0 + m;
  const int ray = p / SAMP;
  const float sc = scaleb[ray];
  const float z  = zbuf[p];
  const float ox = rays[ray*6+0], oy = rays[ray*6+1], oz = rays[ray*6+2];
  const float dx = rays[ray*6+3], dy = rays[ray*6+4], dz = rays[ray*6+5];
  const float x0 = (ox + dx*z/sc)/200.f;
  const float x1 = (oy + dy*z/sc)/200.f;
  const float x2 = (oz + dz*z/sc)/200.f;
  const float u0 = dx/sc, u1 = dy/sc, u2 = dz/sc;
  // x_enc -> buf cols 256..319 (row m, cols 256+g*16..+15, two 16B writes)
  {
    union { _Float16 hv[8]; half8 v; } u8;
#pragma unroll
    for (int hf = 0; hf < 2; ++hf) {
      const int j0 = g*16 + hf*8;
#pragma unroll
      for (int jj = 0; jj < 8; ++jj) u8.hv[jj] = (_Float16)xenc_val(j0+jj, x0, x1, x2);
      *(half8*)(smem + laddr(m, 256 + j0)) = u8.v;
    }
  }
  __syncthreads();
  // L0: reads cols 256..319, writes 0..255 (disjoint)
  gemm<4 ,2,0,true ,256,false>(smem, wt+WT0_OFF,         0, bias+0,    p0, sigmaws, semws); __syncthreads();
  gemm<16,2,0,true ,0  ,true >(smem, wt+WTH_OFF+0*65536, 0, bias+256,  p0, sigmaws, semws); __syncthreads();
  gemm<16,2,0,true ,0  ,true >(smem, wt+WTH_OFF+1*65536, 0, bias+512,  p0, sigmaws, semws); __syncthreads();
  gemm<16,2,0,true ,0  ,true >(smem, wt+WTH_OFF+2*65536, 0, bias+768,  p0, sigmaws, semws); __syncthreads();
  // skip: reads cols 0..319 (h + x_enc), writes 0..255 in place
  gemm<20,2,0,true ,0  ,true >(smem, wt+WTS_OFF,         0, bias+1024, p0, sigmaws, semws);
  // d_enc -> cols 256..287 (x_enc dead; skip's reads all done at its barrier)
  {
    union { _Float16 hv[8]; half8 v; } u8;
    const int c0 = g*8;
#pragma unroll
    for (int cc = 0; cc < 8; ++cc) u8.hv[cc] = (_Float16)denc_val(c0+cc, u0, u1, u2);
    *(half8*)(smem + laddr(m, 256 + c0)) = u8.v;
  }
  __syncthreads();
  gemm<16,2,0,true ,0  ,true >(smem, wt+WTH_OFF+3*65536, 0, bias+1280, p0, sigmaws, semws); __syncthreads();
  gemm<16,2,0,true ,0  ,true >(smem, wt+WTH_OFF+4*65536, 0, bias+1536, p0, sigmaws, semws); __syncthreads();
  gemm<16,2,0,true ,0  ,true >(smem, wt+WTH_OFF+5*65536, 0, bias+1792, p0, sigmaws, semws); __syncthreads();
  // head tail (sem/sigma, frags 8,9): waves 0,1; reads buf, writes global only
  if ((t >> 6) < 2)
    gemm<16,1,1,false,0 ,false>(smem, wt+WTHD_OFF,        8, bias+2048, p0, sigmaws, semws);
  // head feat (cols 0..255) -> in place; its internal barrier also fences tail
  gemm<16,2,0,false,0  ,true >(smem, wt+WTHD_OFF,        0, bias+2048, p0, sigmaws, semws); __syncthreads();
  // rgb1: reads cols 0..287 (feat + d_enc), writes 0..127 in place
  gemm<18,1,0,true ,0  ,true >(smem, wt+WTR1_OFF,        0, bias+2368, p0, sigmaws, semws); __syncthreads();
  gemm_rgb2(smem, wt+WTR2_OFF, bias+2496, p0, rgbws);
}

// ============================================================== compositing
__global__ __launch_bounds__(128) void comp_kernel(
    const float* __restrict__ inter, const float* __restrict__ zbuf,
    const float* __restrict__ scaleb, const float* __restrict__ sigmaws,
    const float* __restrict__ rgbws, const _Float16* __restrict__ semws,
    float* __restrict__ out)
{
  __shared__ float zt[84], alpha[84], wgt[84];
  const int ray = blockIdx.x, t = threadIdx.x;
  const float sc = scaleb[ray];
  const float* bx = inter + (size_t)ray*40;
  if (t < 84) zt[t] = zbuf[(size_t)ray*84 + t] / sc;
  __syncthreads();
  if (t < 84) {
    const float z = zbuf[(size_t)ray*84 + t];
    bool inside = false, bound = false;
    for (int b = 0; b < 10; ++b) {
      const float nr = bx[b*4], fr = bx[b*4+1];
      inside = inside || (z > nr && z < fr);
      const float d1 = z - fr, d2 = nr - z;
      bound = bound || (d1 > 0.f && d1 < 1e-3f) || (d2 > 0.f && d2 < 1e-3f);
    }
    float sg = sigmaws[(size_t)ray*84 + t];
    const bool bbox = (z < 200.f) && !inside;
    if (bbox || bound) sg = 0.f;
    sg = fmaxf(sg, 0.f);
    const float dist = (t < 83) ? (zt[t+1] - zt[t])*sc : 1e10f*sc;
    alpha[t] = 1.f - expf(-sg*dist);
  }
  __syncthreads();
  if (t == 0) {
    float T = 1.f;
    for (int s = 0; s < 84; ++s) { wgt[s] = alpha[s]*T; T *= (1.f - alpha[s] + 1e-10f); }
  }
  __syncthreads();
  if (t < 55) {
    float a = 0.f;
    const size_t base = (size_t)ray*84;
    if (t < 50) {
      for (int s = 0; s < 84; ++s) a += wgt[s]*(float)semws[(base+s)*SEMSTR + t];
      out[(size_t)ray*55 + 5 + t] = a;
    } else if (t < 53) {
      const int c = t - 50;
      for (int s = 0; s < 84; ++s) { const float r = rgbws[(base+s)*3 + c]; a += wgt[s]/(1.f + expf(-r)); }
      out[(size_t)ray*55 + c] = a;
    } else if (t == 53) {
      for (int s = 0; s < 84; ++s) a += wgt[s]*zt[s];
      out[(size_t)ray*55 + 3] = a;
    } else {
      for (int s = 0; s < 84; ++s) a += wgt[s];
      out[(size_t)ray*55 + 4] = a;
    }
  }
}

// ============================================================== launch
extern "C" void kernel_launch(void* const* d_in, const int* in_sizes, int n_in,
                              void* d_out, int out_size, void* d_ws, size_t ws_size,
                              hipStream_t stream) {
  const float* rays   = (const float*)d_in[0];
  const float* inter  = (const float*)d_in[1];
  const float* noise  = (const float*)d_in[2];
  const float* w_in   = (const float*)d_in[3];
  const float* b_in   = (const float*)d_in[4];
  const float* w_h    = (const float*)d_in[5];
  const float* b_h    = (const float*)d_in[6];
  const float* w_skip = (const float*)d_in[7];
  const float* b_skip = (const float*)d_in[8];
  const float* w_sig  = (const float*)d_in[9];
  const float* b_sig  = (const float*)d_in[10];
  const float* w_feat = (const float*)d_in[11];
  const float* b_feat = (const float*)d_in[12];
  const float* w_rgb1 = (const float*)d_in[13];
  const float* b_rgb1 = (const float*)d_in[14];
  const float* w_rgb2 = (const float*)d_in[15];
  const float* b_rgb2 = (const float*)d_in[16];
  const float* w_sem  = (const float*)d_in[17];
  const float* b_sem  = (const float*)d_in[18];

  uint8_t* ws = (uint8_t*)d_ws;
  _Float16* wt    = (_Float16*)(ws + OFF_WT);
  float* bias     = (float*)(ws + OFF_BIAS);
  float* zbuf     = (float*)(ws + OFF_Z);
  float* scaleb   = (float*)(ws + OFF_SCALE);
  float* sigmaws  = (float*)(ws + OFF_SIGMA);
  float* rgbws    = (float*)(ws + OFF_RGB);
  _Float16* semws = (_Float16*)(ws + OFF_SEM);

  prep_kernel<<<dim3((WT_TOTAL + NBIAS + 255)/256), dim3(256), 0, stream>>>(
      w_in, w_h, w_skip, w_sig, w_feat, w_rgb1, w_rgb2, w_sem,
      b_in, b_h, b_skip, b_sig, b_feat, b_rgb1, b_rgb2, b_sem, wt, bias);
  sample_kernel<<<dim3(NRAYS), dim3(256), 0, stream>>>(rays, inter, noise, zbuf, scaleb);
  mlp_kernel<<<dim3(NPTS/64), dim3(256), LDS_TOTAL, stream>>>(
      rays, zbuf, scaleb, wt, bias, sigmaws, rgbws, semws);
  comp_kernel<<<dim3(NRAYS), dim3(128), 0, stream>>>(
      inter, zbuf, scaleb, sigmaws, rgbws, semws, (float*)d_out);
}

// Round 11
// 278.998 us; speedup vs baseline: 1.0488x; 1.0488x over previous
//
#include <hip/hip_runtime.h>

typedef _Float16 half8 __attribute__((ext_vector_type(8)));
typedef __fp16  half2v __attribute__((ext_vector_type(2)));
typedef float f32x4  __attribute__((ext_vector_type(4)));
typedef float f32x16 __attribute__((ext_vector_type(16)));

#define NRAYS 2048
#define SAMP 84
#define NPTS (NRAYS*SAMP)   // 172032
#define SEMSTR 52           // padded sem row stride (halves)

// ---- half-element offsets inside the weight region ----
// pack: [frag F(32 cols)][kt(K16)][lane l(64)][h(8 halves)] ;
//   n = F*32 + (l&31), k = kt*16 + (l>>5)*8 + h
#define WT0_OFF   0         // 8 frags x KT4
#define WTH_OFF   16384     // 6 x (8 frags x KT16)
#define WTS_OFF   409600    // 8 frags x KT20
#define WTHD_OFF  491520    // 10 frags x KT16
#define WTR1_OFF  573440    // 4 frags x KT18
#define WTR2_OFF  610304    // 1 frag x KT8
#define WT_TOTAL  614400
#define NBIAS     2512

// ---- ws byte offsets ----
#define OFF_WT    ((size_t)0)
#define OFF_BIAS  ((size_t)1228800)                 // WT_TOTAL*2
#define OFF_BIASH ((size_t)1238848)                 // OFF_BIAS + NBIAS*4
#define OFF_Z     ((size_t)1243904)                 // OFF_BIASH + NBIAS*2 (padded)
#define OFF_SCALE (OFF_Z + (size_t)NPTS*4)
#define OFF_SIGMA (OFF_SCALE + (size_t)NRAYS*4)
#define OFF_RGB   (OFF_SIGMA + (size_t)NPTS*4)
#define OFF_SEM   (OFF_RGB + (size_t)NPTS*12)

// ============================================================== prep
__global__ __launch_bounds__(256) void prep_kernel(
    const float* __restrict__ w_in,  const float* __restrict__ w_h,
    const float* __restrict__ w_skip,const float* __restrict__ w_sigma,
    const float* __restrict__ w_feat,const float* __restrict__ w_rgb1,
    const float* __restrict__ w_rgb2,const float* __restrict__ w_sem,
    const float* __restrict__ b_in,  const float* __restrict__ b_h,
    const float* __restrict__ b_skip,const float* __restrict__ b_sigma,
    const float* __restrict__ b_feat,const float* __restrict__ b_rgb1,
    const float* __restrict__ b_rgb2,const float* __restrict__ b_sem,
    _Float16* __restrict__ wt, float* __restrict__ bias,
    _Float16* __restrict__ biasH)
{
  int idx = blockIdx.x*256 + threadIdx.x;
  if (idx < WT_TOTAL) {
    float v; int n, k, l, h, kt, F, rem;
    if (idx < WTH_OFF) {                 // L0: 8 frags x KT4 (2048/frag)
      F = idx >> 11; rem = idx & 2047; kt = rem >> 9; int q = rem & 511;
      l = q >> 3; h = q & 7;
      n = F*32 + (l&31); k = kt*16 + ((l>>5)<<3) + h;
      v = (k < 63) ? w_in[k*256 + n] : 0.f;
    } else if (idx < WTS_OFF) {          // hidden: 6 x (8 frags x KT16)
      int r = idx - WTH_OFF; int i = r >> 16; int rr = r & 65535;
      F = rr >> 13; rem = rr & 8191; kt = rem >> 9; int q = rem & 511;
      l = q >> 3; h = q & 7;
      n = F*32 + (l&31); k = kt*16 + ((l>>5)<<3) + h;
      v = w_h[(i<<16) + (k<<8) + n];
    } else if (idx < WTHD_OFF) {         // skip: 8 frags x KT20 (10240/frag)
      int r = idx - WTS_OFF;
      F = r / 10240; rem = r % 10240; kt = rem >> 9; int q = rem & 511;
      l = q >> 3; h = q & 7;
      n = F*32 + (l&31); k = kt*16 + ((l>>5)<<3) + h;
      v = (k < 319) ? w_skip[k*256 + n] : 0.f;
    } else if (idx < WTR1_OFF) {         // head: 10 frags x KT16
      int r = idx - WTHD_OFF;
      F = r >> 13; rem = r & 8191; kt = rem >> 9; int q = rem & 511;
      l = q >> 3; h = q & 7;
      n = F*32 + (l&31); k = kt*16 + ((l>>5)<<3) + h;
      v = (n < 256) ? w_feat[(k<<8) + n]
        : (n < 306) ? w_sem[k*50 + (n-256)]
        : (n == 306)? w_sigma[k] : 0.f;
    } else if (idx < WTR2_OFF) {         // rgb1: 4 frags x KT18 (9216/frag)
      int r = idx - WTR1_OFF;
      F = r / 9216; rem = r % 9216; kt = rem >> 9; int q = rem & 511;
      l = q >> 3; h = q & 7;
      n = F*32 + (l&31); k = kt*16 + ((l>>5)<<3) + h;
      v = (k < 283) ? w_rgb1[k*128 + n] : 0.f;
    } else {                             // rgb2: 1 frag x KT8
      int r = idx - WTR2_OFF;
      kt = r >> 9; int q = r & 511;
      l = q >> 3; h = q & 7;
      n = (l&31); k = kt*16 + ((l>>5)<<3) + h;
      v = (n < 3) ? w_rgb2[k*3 + n] : 0.f;
    }
    wt[idx] = (_Float16)v;
  } else if (idx < WT_TOTAL + NBIAS) {
    int j = idx - WT_TOTAL; float v;
    if (j < 2048) {
      int i = j >> 8, c = j & 255;
      v = (i==0) ? b_in[c] : (i<4) ? b_h[(i-1)*256+c]
        : (i==4) ? b_skip[c] : b_h[(i-2)*256+c];
    } else if (j < 2368) {
      int c = j - 2048;
      v = (c<256) ? b_feat[c] : (c<306) ? b_sem[c-256]
        : (c==306) ? b_sigma[0] : 0.f;
    } else if (j < 2496) v = b_rgb1[j-2368];
    else { int c = j-2496; v = (c<3) ? b_rgb2[c] : 0.f; }
    bias[j] = v;
    biasH[j] = (_Float16)v;
  }
}

// ============================================================== sampling
__global__ __launch_bounds__(256) void sample_kernel(
    const float* __restrict__ rays, const float* __restrict__ inter,
    const float* __restrict__ noise, float* __restrict__ zbuf,
    float* __restrict__ scaleb)
{
  __shared__ float sv[240], ss[240], z2[84];
  const int ray = blockIdx.x, t = threadIdx.x;
  const float* bx = inter + (size_t)ray*40;
  if (t < 240) {
    int b = t/24, j = t%24;
    float nr = bx[b*4], fr = bx[b*4+1];
    float tj = (j==23) ? 1.f : (float)j * (1.f/23.f);
    sv[t] = nr + (fr-nr)*tj;
  }
  __syncthreads();
  if (t < 240) {
    float v = sv[t]; int r = 0;
    for (int i = 0; i < 240; ++i) { float vi = sv[i]; r += (vi < v) || (vi == v && i < t); }
    ss[r] = v;
  }
  __syncthreads();
  if (t < 64) {
    float z;
    if (t == 63) z = ss[239];
    else { int num = t*239; int k = num/63; float f = (float)(num - k*63)*(1.f/63.f);
           z = ss[k] + f*(ss[k+1]-ss[k]); }
    z2[t] = z;
  } else if (t < 84) {
    int b = t - 64;
    z2[t] = (b < 10) ? (bx[b*4] - 1e-5f) : (bx[(b-10)*4+1] + 1e-5f);
  }
  __syncthreads();
  if (t < 84) { float z = z2[t]; if (z < 0.f) z = 200.f + 20.f*noise[(size_t)ray*84 + t]; z2[t] = z; }
  __syncthreads();
  if (t < 84) {
    float v = z2[t]; int r = 0;
    for (int i = 0; i < 84; ++i) { float vi = z2[i]; r += (vi < v) || (vi == v && i < t); }
    zbuf[(size_t)ray*84 + r] = v;
  }
  if (t == 0) {
    float dx = rays[ray*6+3], dy = rays[ray*6+4], dz = rays[ray*6+5];
    scaleb[ray] = sqrtf(dx*dx + dy*dy + dz*dz);
  }
}

// ============================================================== MLP
// 128 pts/block, 256 threads = 4 waves, pure n-split. mfma_f32_32x32x16_f16.
// Per wave: NF=2 frags of 32 cols (64 cols), MF=4 row-tiles of 32 (all 128 rows).
// Single in-place buffer: [128 rows][320 cols] f16, stride 640B, 16B-chunk XOR
// swizzle. 80KB -> 2 blocks/CU (exact 160KB fit). x_enc/d_enc live in cols 256+.
#define LDS_TOTAL 81920

__device__ __forceinline__ uint32_t laddr(int m, int k) {
  return (uint32_t)(m*640) + (uint32_t)((((k>>3)^(m&7))<<4) + ((k&7)<<1));
}
struct __attribute__((aligned(8))) H4 { _Float16 h[4]; };

__device__ __forceinline__ float xenc_val(int j, float x0, float x1, float x2) {
  if (j >= 63) return 0.f;
  if (j < 3) return j==0?x0:(j==1?x1:x2);
  int q = j-3, lf = q/6, r = q%6, ci = r%3;
  float xc = (ci==0)?x0:((ci==1)?x1:x2);
  float arg = xc * (float)(1<<lf);
  return (r<3) ? sinf(arg) : cosf(arg);
}
__device__ __forceinline__ float denc_val(int c, float u0, float u1, float u2) {
  if (c >= 27) return 0.f;
  if (c < 3) return c==0?u0:(c==1?u1:u2);
  int q = c-3, lf = q/6, r = q%6, ci = r%3;
  float uc = (ci==0)?u0:((ci==1)?u1:u2);
  float arg = uc * (float)(1<<lf);
  return (r<3) ? sinf(arg) : cosf(arg);
}

// 4 waves, wave wn: frags [fbase+wn*NF, +NF), rows 0..127 (MF=4 tiles of 32).
// KT = number of K16 steps. XOFF = column base of the K-input in buf.
// MODE 0: write f16 frags back to buf (opt RELU), packed-f16 bias.
// MODE 1: sem/sigma -> global, f32 bias.
// INPLACE: __syncthreads() after the MFMA loop (all reads) before LDS writes.
// Weight ring depth 4, lead 3; B double-buffered.
template<int KT, int NF, int MODE, bool RELU, int XOFF, bool INPLACE>
__device__ __forceinline__ void gemm(uint8_t* smem,
    const _Float16* __restrict__ WT, int fbase,
    const float* __restrict__ bias0, const _Float16* __restrict__ biasH0,
    int p0, float* __restrict__ sigmaws, _Float16* __restrict__ semws)
{
  constexpr int MF = 4;
  const int t = threadIdx.x;
  const int l = t & 63, wn = t >> 6;
  const int lr = l & 31, lg = l >> 5;
  constexpr int DW   = (KT <= 3) ? KT : 4;
  constexpr int LEAD = (KT <= 3) ? KT : 3;
  f32x16 acc[NF][MF];
#pragma unroll
  for (int i = 0; i < NF; ++i)
#pragma unroll
    for (int j = 0; j < MF; ++j)
#pragma unroll
      for (int r = 0; r < 16; ++r) acc[i][j][r] = 0.f;
  const _Float16* wb = WT + (size_t)((fbase + wn*NF)*KT)*512 + (size_t)l*8;
  half8 av[DW][NF];
  half8 bv[2][MF];
  auto baddr = [&](int mf, int kt)->uint32_t {
    return laddr(mf*32 + lr, XOFF + kt*16 + lg*8);
  };
  // prologue: weights kt=0..LEAD-1, activations kt=0
#pragma unroll
  for (int d = 0; d < LEAD && d < KT; ++d)
#pragma unroll
    for (int nf = 0; nf < NF; ++nf)
      av[d][nf] = *(const half8*)(wb + (size_t)(nf*KT + d)*512);
#pragma unroll
  for (int mf = 0; mf < MF; ++mf)
    bv[0][mf] = *(const half8*)(smem + baddr(mf, 0));
#pragma unroll
  for (int kt = 0; kt < KT; ++kt) {
    if (kt + 1 < KT) {
#pragma unroll
      for (int mf = 0; mf < MF; ++mf)
        bv[(kt+1)&1][mf] = *(const half8*)(smem + baddr(mf, kt+1));
    }
    if (kt + LEAD < KT) {
#pragma unroll
      for (int nf = 0; nf < NF; ++nf)
        av[(kt+LEAD)%DW][nf] = *(const half8*)(wb + (size_t)(nf*KT + kt + LEAD)*512);
    }
    __builtin_amdgcn_sched_barrier(0);
#pragma unroll
    for (int nf = 0; nf < NF; ++nf)
#pragma unroll
      for (int mf = 0; mf < MF; ++mf)
        acc[nf][mf] = __builtin_amdgcn_mfma_f32_32x32x16_f16(
            av[kt%DW][nf], bv[kt&1][mf], acc[nf][mf], 0, 0, 0);
    __builtin_amdgcn_sched_barrier(0);
  }
  if (INPLACE) __syncthreads();   // all reads of buf done -> safe to overwrite
  // D layout (32x32): row m = mtile*32 + (lane&31);
  // col n = ncol0 + (r&3) + 8*(r>>2) + 4*(lane>>5), r in [0,16)
#pragma unroll
  for (int nf = 0; nf < NF; ++nf) {
    const int ncol0 = (fbase + wn*NF + nf)*32;
#pragma unroll
    for (int mf = 0; mf < MF; ++mf) {
      const int m = mf*32 + lr;
      const f32x16 v = acc[nf][mf];
#pragma unroll
      for (int g = 0; g < 4; ++g) {
        const int nst = ncol0 + 8*g + 4*lg;
        if (MODE == 0) {
          half2v h0 = __builtin_amdgcn_cvt_pkrtz(v[4*g+0], v[4*g+1]);
          half2v h1 = __builtin_amdgcn_cvt_pkrtz(v[4*g+2], v[4*g+3]);
          const half2v* bh = (const half2v*)(biasH0 + nst);
          h0 = h0 + bh[0];
          h1 = h1 + bh[1];
          if (RELU) {
            h0 = __builtin_elementwise_max(h0, (half2v)(__fp16)0);
            h1 = __builtin_elementwise_max(h1, (half2v)(__fp16)0);
          }
          H4 hh; *(half2v*)&hh.h[0] = h0; *(half2v*)&hh.h[2] = h1;
          *(H4*)(smem + laddr(m, nst)) = hh;
        } else {
          const f32x4 b4 = *(const f32x4*)(bias0 + nst);
          float y0 = v[4*g+0] + b4[0], y1 = v[4*g+1] + b4[1];
          float y2 = v[4*g+2] + b4[2], y3 = v[4*g+3] + b4[3];
          const int cb = nst - 256;
          const int pp = p0 + m;
          if (cb <= 44) {
            H4 hh; hh.h[0]=(_Float16)y0; hh.h[1]=(_Float16)y1;
                   hh.h[2]=(_Float16)y2; hh.h[3]=(_Float16)y3;
            *(H4*)(semws + (size_t)pp*SEMSTR + cb) = hh;
          } else if (cb == 48) {
            semws[(size_t)pp*SEMSTR + 48] = (_Float16)y0;
            semws[(size_t)pp*SEMSTR + 49] = (_Float16)y1;
            sigmaws[pp] = y2;
          }
        }
      }
    }
  }
}

__device__ __forceinline__ void gemm_rgb2(uint8_t* smem,
    const _Float16* __restrict__ WT, const float* __restrict__ bias,
    int p0, float* __restrict__ rgbws)
{
  const int t = threadIdx.x;
  const int l = t & 63, w = t >> 6;     // 4 waves x 32 rows = 128 pts
  const int lr = l & 31, lg = l >> 5;
  f32x16 acc;
#pragma unroll
  for (int r = 0; r < 16; ++r) acc[r] = 0.f;
  const _Float16* wb = WT + (size_t)l*8;
#pragma unroll
  for (int kt = 0; kt < 8; ++kt) {
    half8 a = *(const half8*)(wb + (size_t)kt*512);
    half8 b = *(const half8*)(smem + laddr(w*32 + lr, kt*16 + lg*8));
    acc = __builtin_amdgcn_mfma_f32_32x32x16_f16(a, b, acc, 0, 0, 0);
  }
  if (lg == 0) {                        // n = r for r<4 when lane>>5 == 0
    const int pp = p0 + w*32 + lr;
#pragma unroll
    for (int r = 0; r < 3; ++r)
      rgbws[(size_t)pp*3 + r] = acc[r] + bias[r];
  }
}

__global__ __launch_bounds__(256,2) void mlp_kernel(
    const float* __restrict__ rays, const float* __restrict__ zbuf,
    const float* __restrict__ scaleb, const _Float16* __restrict__ wt,
    const float* __restrict__ bias, const _Float16* __restrict__ biasH,
    float* __restrict__ sigmaws, float* __restrict__ rgbws,
    _Float16* __restrict__ semws)
{
  extern __shared__ uint8_t smem[];
  const int p0 = blockIdx.x*128;
  const int t = threadIdx.x;
  const int m = t & 127, g = t >> 7;    // 2 threads per row
  const int p = p0 + m;
  const int ray = p / SAMP;
  const float sc = scaleb[ray];
  const float z  = zbuf[p];
  const float ox = rays[ray*6+0], oy = rays[ray*6+1], oz = rays[ray*6+2];
  const float dx = rays[ray*6+3], dy = rays[ray*6+4], dz = rays[ray*6+5];
  const float x0 = (ox + dx*z/sc)/200.f;
  const float x1 = (oy + dy*z/sc)/200.f;
  const float x2 = (oz + dz*z/sc)/200.f;
  const float u0 = dx/sc, u1 = dy/sc, u2 = dz/sc;
  // x_enc -> buf cols 256..319 (row m, 32 cols per thread, 4x 16B writes)
  {
    union { _Float16 hv[8]; half8 v; } u8;
#pragma unroll
    for (int q = 0; q < 4; ++q) {
      const int j0 = g*32 + q*8;
#pragma unroll
      for (int jj = 0; jj < 8; ++jj) u8.hv[jj] = (_Float16)xenc_val(j0+jj, x0, x1, x2);
      *(half8*)(smem + laddr(m, 256 + j0)) = u8.v;
    }
  }
  __syncthreads();
  // L0: reads cols 256..319, writes 0..255 (disjoint)
  gemm<4 ,2,0,true ,256,false>(smem, wt+WT0_OFF,         0, bias+0,    biasH+0,    p0, sigmaws, semws); __syncthreads();
  gemm<16,2,0,true ,0  ,true >(smem, wt+WTH_OFF+0*65536, 0, bias+256,  biasH+256,  p0, sigmaws, semws); __syncthreads();
  gemm<16,2,0,true ,0  ,true >(smem, wt+WTH_OFF+1*65536, 0, bias+512,  biasH+512,  p0, sigmaws, semws); __syncthreads();
  gemm<16,2,0,true ,0  ,true >(smem, wt+WTH_OFF+2*65536, 0, bias+768,  biasH+768,  p0, sigmaws, semws); __syncthreads();
  // skip: reads cols 0..319 (h + x_enc), writes 0..255 in place
  gemm<20,2,0,true ,0  ,true >(smem, wt+WTS_OFF,         0, bias+1024, biasH+1024, p0, sigmaws, semws);
  // d_enc -> cols 256..287 (x_enc dead; skip's reads fenced by its barrier)
  {
    union { _Float16 hv[8]; half8 v; } u8;
#pragma unroll
    for (int hf = 0; hf < 2; ++hf) {
      const int c0 = g*16 + hf*8;
#pragma unroll
      for (int cc = 0; cc < 8; ++cc) u8.hv[cc] = (_Float16)denc_val(c0+cc, u0, u1, u2);
      *(half8*)(smem + laddr(m, 256 + c0)) = u8.v;
    }
  }
  __syncthreads();
  gemm<16,2,0,true ,0  ,true >(smem, wt+WTH_OFF+3*65536, 0, bias+1280, biasH+1280, p0, sigmaws, semws); __syncthreads();
  gemm<16,2,0,true ,0  ,true >(smem, wt+WTH_OFF+4*65536, 0, bias+1536, biasH+1536, p0, sigmaws, semws); __syncthreads();
  gemm<16,2,0,true ,0  ,true >(smem, wt+WTH_OFF+5*65536, 0, bias+1792, biasH+1792, p0, sigmaws, semws); __syncthreads();
  // head tail (sem/sigma, frags 8,9): waves 0,1; reads buf, writes global only
  if ((t >> 6) < 2)
    gemm<16,1,1,false,0 ,false>(smem, wt+WTHD_OFF,        8, bias+2048, biasH+2048, p0, sigmaws, semws);
  // head feat (cols 0..255) -> in place; its internal barrier fences the tail
  gemm<16,2,0,false,0  ,true >(smem, wt+WTHD_OFF,        0, bias+2048, biasH+2048, p0, sigmaws, semws); __syncthreads();
  // rgb1: reads cols 0..287 (feat + d_enc), writes 0..127 in place
  gemm<18,1,0,true ,0  ,true >(smem, wt+WTR1_OFF,        0, bias+2368, biasH+2368, p0, sigmaws, semws); __syncthreads();
  gemm_rgb2(smem, wt+WTR2_OFF, bias+2496, p0, rgbws);
}

// ============================================================== compositing
__global__ __launch_bounds__(128) void comp_kernel(
    const float* __restrict__ inter, const float* __restrict__ zbuf,
    const float* __restrict__ scaleb, const float* __restrict__ sigmaws,
    const float* __restrict__ rgbws, const _Float16* __restrict__ semws,
    float* __restrict__ out)
{
  __shared__ float zt[84], alpha[84], wgt[84];
  const int ray = blockIdx.x, t = threadIdx.x;
  const float sc = scaleb[ray];
  const float* bx = inter + (size_t)ray*40;
  if (t < 84) zt[t] = zbuf[(size_t)ray*84 + t] / sc;
  __syncthreads();
  if (t < 84) {
    const float z = zbuf[(size_t)ray*84 + t];
    bool inside = false, bound = false;
    for (int b = 0; b < 10; ++b) {
      const float nr = bx[b*4], fr = bx[b*4+1];
      inside = inside || (z > nr && z < fr);
      const float d1 = z - fr, d2 = nr - z;
      bound = bound || (d1 > 0.f && d1 < 1e-3f) || (d2 > 0.f && d2 < 1e-3f);
    }
    float sg = sigmaws[(size_t)ray*84 + t];
    const bool bbox = (z < 200.f) && !inside;
    if (bbox || bound) sg = 0.f;
    sg = fmaxf(sg, 0.f);
    const float dist = (t < 83) ? (zt[t+1] - zt[t])*sc : 1e10f*sc;
    alpha[t] = 1.f - expf(-sg*dist);
  }
  __syncthreads();
  if (t == 0) {
    float T = 1.f;
    for (int s = 0; s < 84; ++s) { wgt[s] = alpha[s]*T; T *= (1.f - alpha[s] + 1e-10f); }
  }
  __syncthreads();
  if (t < 55) {
    float a = 0.f;
    const size_t base = (size_t)ray*84;
    if (t < 50) {
      for (int s = 0; s < 84; ++s) a += wgt[s]*(float)semws[(base+s)*SEMSTR + t];
      out[(size_t)ray*55 + 5 + t] = a;
    } else if (t < 53) {
      const int c = t - 50;
      for (int s = 0; s < 84; ++s) { const float r = rgbws[(base+s)*3 + c]; a += wgt[s]/(1.f + expf(-r)); }
      out[(size_t)ray*55 + c] = a;
    } else if (t == 53) {
      for (int s = 0; s < 84; ++s) a += wgt[s]*zt[s];
      out[(size_t)ray*55 + 3] = a;
    } else {
      for (int s = 0; s < 84; ++s) a += wgt[s];
      out[(size_t)ray*55 + 4] = a;
    }
  }
}

// ============================================================== launch
extern "C" void kernel_launch(void* const* d_in, const int* in_sizes, int n_in,
                              void* d_out, int out_size, void* d_ws, size_t ws_size,
                              hipStream_t stream) {
  const float* rays   = (const float*)d_in[0];
  const float* inter  = (const float*)d_in[1];
  const float* noise  = (const float*)d_in[2];
  const float* w_in   = (const float*)d_in[3];
  const float* b_in   = (const float*)d_in[4];
  const float* w_h    = (const float*)d_in[5];
  const float* b_h    = (const float*)d_in[6];
  const float* w_skip = (const float*)d_in[7];
  const float* b_skip = (const float*)d_in[8];
  const float* w_sig  = (const float*)d_in[9];
  const float* b_sig  = (const float*)d_in[10];
  const float* w_feat = (const float*)d_in[11];
  const float* b_feat = (const float*)d_in[12];
  const float* w_rgb1 = (const float*)d_in[13];
  const float* b_rgb1 = (const float*)d_in[14];
  const float* w_rgb2 = (const float*)d_in[15];
  const float* b_rgb2 = (const float*)d_in[16];
  const float* w_sem  = (const float*)d_in[17];
  const float* b_sem  = (const float*)d_in[18];

  uint8_t* ws = (uint8_t*)d_ws;
  _Float16* wt    = (_Float16*)(ws + OFF_WT);
  float* bias     = (float*)(ws + OFF_BIAS);
  _Float16* biasH = (_Float16*)(ws + OFF_BIASH);
  float* zbuf     = (float*)(ws + OFF_Z);
  float* scaleb   = (float*)(ws + OFF_SCALE);
  float* sigmaws  = (float*)(ws + OFF_SIGMA);
  float* rgbws    = (float*)(ws + OFF_RGB);
  _Float16* semws = (_Float16*)(ws + OFF_SEM);

  prep_kernel<<<dim3((WT_TOTAL + NBIAS + 255)/256), dim3(256), 0, stream>>>(
      w_in, w_h, w_skip, w_sig, w_feat, w_rgb1, w_rgb2, w_sem,
      b_in, b_h, b_skip, b_sig, b_feat, b_rgb1, b_rgb2, b_sem, wt, bias, biasH);
  sample_kernel<<<dim3(NRAYS), dim3(256), 0, stream>>>(rays, inter, noise, zbuf, scaleb);
  mlp_kernel<<<dim3(NPTS/128), dim3(256), LDS_TOTAL, stream>>>(
      rays, zbuf, scaleb, wt, bias, biasH, sigmaws, rgbws, semws);
  comp_kernel<<<dim3(NRAYS), dim3(128), 0, stream>>>(
      inter, zbuf, scaleb, sigmaws, rgbws, semws, (float*)d_out);
}

// Round 12
// 268.147 us; speedup vs baseline: 1.0912x; 1.0405x over previous
//
#include <hip/hip_runtime.h>

typedef _Float16 half8 __attribute__((ext_vector_type(8)));
typedef __fp16  half2v __attribute__((ext_vector_type(2)));
typedef float f32x4 __attribute__((ext_vector_type(4)));

#define NRAYS 2048
#define SAMP 84
#define NPTS (NRAYS*SAMP)   // 172032
#define SEMSTR 52           // padded sem row stride (halves)

// ---- half-element offsets inside the weight region (fragment-packed) ----
// layout per region: [frag F][kt][lane l][h 0..7] ; n = F*16 + (l&15), k = kt*32 + (l>>4)*8 + h
#define WT0_OFF   0         // 16 frags x KT2
#define WTH_OFF   16384     // 6 x (16 frags x KT8)
#define WTS_OFF   409600    // 16 frags x KT10
#define WTHD_OFF  491520    // 20 frags x KT8
#define WTR1_OFF  573440    // 8 frags x KT9
#define WTR2_OFF  610304    // 1 frag x KT4
#define WT_TOTAL  612352
#define NBIAS     2512

// ---- ws byte offsets ----
#define OFF_WT    ((size_t)0)
#define OFF_BIAS  ((size_t)1224704)                 // WT_TOTAL*2
#define OFF_BIASH ((size_t)1234752)                 // OFF_BIAS + NBIAS*4
#define OFF_Z     ((size_t)1239808)                 // OFF_BIASH + NBIAS*2 (padded)
#define OFF_SCALE (OFF_Z + (size_t)NPTS*4)
#define OFF_SIGMA (OFF_SCALE + (size_t)NRAYS*4)
#define OFF_RGB   (OFF_SIGMA + (size_t)NPTS*4)
#define OFF_SEM   (OFF_RGB + (size_t)NPTS*12)

// ============================================================== prep
__global__ __launch_bounds__(256) void prep_kernel(
    const float* __restrict__ w_in,  const float* __restrict__ w_h,
    const float* __restrict__ w_skip,const float* __restrict__ w_sigma,
    const float* __restrict__ w_feat,const float* __restrict__ w_rgb1,
    const float* __restrict__ w_rgb2,const float* __restrict__ w_sem,
    const float* __restrict__ b_in,  const float* __restrict__ b_h,
    const float* __restrict__ b_skip,const float* __restrict__ b_sigma,
    const float* __restrict__ b_feat,const float* __restrict__ b_rgb1,
    const float* __restrict__ b_rgb2,const float* __restrict__ b_sem,
    _Float16* __restrict__ wt, float* __restrict__ bias,
    _Float16* __restrict__ biasH)
{
  int idx = blockIdx.x*256 + threadIdx.x;
  if (idx < WT_TOTAL) {
    float v; int n, k, l, h, q;
    if (idx < WTH_OFF) {                 // L0: 16 frags, KT=2
      int r = idx; int F = r >> 10; int rem = r & 1023; int kt = rem >> 9; q = rem & 511;
      l = q >> 3; h = q & 7;
      n = F*16 + (l&15); k = kt*32 + (l>>4)*8 + h;
      v = (k < 63) ? w_in[k*256 + n] : 0.f;
    } else if (idx < WTS_OFF) {          // hidden: 6 x (16 frags x KT8)
      int r = idx - WTH_OFF; int i = r >> 16; int r2 = r & 65535;
      int F = r2 >> 12; int kt = (r2 >> 9) & 7; q = r2 & 511;
      l = q >> 3; h = q & 7;
      n = F*16 + (l&15); k = kt*32 + (l>>4)*8 + h;
      v = w_h[(i<<16) + (k<<8) + n];
    } else if (idx < WTHD_OFF) {         // skip: 16 frags x KT10
      int r = idx - WTS_OFF; int F = r / 5120; int rem = r % 5120; int kt = rem >> 9; q = rem & 511;
      l = q >> 3; h = q & 7;
      n = F*16 + (l&15); k = kt*32 + (l>>4)*8 + h;
      v = (k < 319) ? w_skip[k*256 + n] : 0.f;
    } else if (idx < WTR1_OFF) {         // head: 20 frags x KT8
      int r = idx - WTHD_OFF; int F = r >> 12; int kt = (r >> 9) & 7; q = r & 511;
      l = q >> 3; h = q & 7;
      n = F*16 + (l&15); k = kt*32 + (l>>4)*8 + h;
      v = (n < 256) ? w_feat[(k<<8) + n]
        : (n < 306) ? w_sem[k*50 + (n-256)]
        : (n == 306)? w_sigma[k] : 0.f;
    } else if (idx < WTR2_OFF) {         // rgb1: 8 frags x KT9
      int r = idx - WTR1_OFF; int F = r / 4608; int rem = r % 4608; int kt = rem >> 9; q = rem & 511;
      l = q >> 3; h = q & 7;
      n = F*16 + (l&15); k = kt*32 + (l>>4)*8 + h;
      v = (k < 283) ? w_rgb1[k*128 + n] : 0.f;
    } else {                             // rgb2: 1 frag x KT4
      int r = idx - WTR2_OFF; int kt = r >> 9; q = r & 511;
      l = q >> 3; h = q & 7;
      n = (l&15); k = kt*32 + (l>>4)*8 + h;
      v = (n < 3) ? w_rgb2[k*3 + n] : 0.f;
    }
    wt[idx] = (_Float16)v;
  } else if (idx < WT_TOTAL + NBIAS) {
    int j = idx - WT_TOTAL; float v;
    if (j < 2048) {
      int i = j >> 8, c = j & 255;
      v = (i==0) ? b_in[c] : (i<4) ? b_h[(i-1)*256+c]
        : (i==4) ? b_skip[c] : b_h[(i-2)*256+c];
    } else if (j < 2368) {
      int c = j - 2048;
      v = (c<256) ? b_feat[c] : (c<306) ? b_sem[c-256]
        : (c==306) ? b_sigma[0] : 0.f;
    } else if (j < 2496) v = b_rgb1[j-2368];
    else { int c = j-2496; v = (c<3) ? b_rgb2[c] : 0.f; }
    bias[j] = v;
    biasH[j] = (_Float16)v;
  }
}

// ============================================================== sampling
__global__ __launch_bounds__(256) void sample_kernel(
    const float* __restrict__ rays, const float* __restrict__ inter,
    const float* __restrict__ noise, float* __restrict__ zbuf,
    float* __restrict__ scaleb)
{
  __shared__ float sv[240], ss[240], z2[84];
  const int ray = blockIdx.x, t = threadIdx.x;
  const float* bx = inter + (size_t)ray*40;
  if (t < 240) {
    int b = t/24, j = t%24;
    float nr = bx[b*4], fr = bx[b*4+1];
    float tj = (j==23) ? 1.f : (float)j * (1.f/23.f);
    sv[t] = nr + (fr-nr)*tj;
  }
  __syncthreads();
  if (t < 240) {
    float v = sv[t]; int r = 0;
    for (int i = 0; i < 240; ++i) { float vi = sv[i]; r += (vi < v) || (vi == v && i < t); }
    ss[r] = v;
  }
  __syncthreads();
  if (t < 64) {
    float z;
    if (t == 63) z = ss[239];
    else { int num = t*239; int k = num/63; float f = (float)(num - k*63)*(1.f/63.f);
           z = ss[k] + f*(ss[k+1]-ss[k]); }
    z2[t] = z;
  } else if (t < 84) {
    int b = t - 64;
    z2[t] = (b < 10) ? (bx[b*4] - 1e-5f) : (bx[(b-10)*4+1] + 1e-5f);
  }
  __syncthreads();
  if (t < 84) { float z = z2[t]; if (z < 0.f) z = 200.f + 20.f*noise[(size_t)ray*84 + t]; z2[t] = z; }
  __syncthreads();
  if (t < 84) {
    float v = z2[t]; int r = 0;
    for (int i = 0; i < 84; ++i) { float vi = z2[i]; r += (vi < v) || (vi == v && i < t); }
    zbuf[(size_t)ray*84 + r] = v;
  }
  if (t == 0) {
    float dx = rays[ray*6+3], dy = rays[ray*6+4], dz = rays[ray*6+5];
    scaleb[ray] = sqrtf(dx*dx + dy*dy + dz*dz);
  }
}

// ============================================================== MLP
// 64 pts/block, 256 threads (4 waves, pure n-split). Per wave: ALL 64 rows x NF*16 cols.
// LDS: bufA (64x256 f16, 32KB) @0, bufB @32768, bufX (64x64 f16, 8KB) @65536. 72KB -> 2 blocks/CU.
#define LDS_A 0u
#define LDS_B 32768u
#define LDS_X 65536u
#define LDS_TOTAL 73728

__device__ __forceinline__ uint32_t laddr(uint32_t base, int m, int k) {
  return base + (uint32_t)(m*512) + (uint32_t)((((k>>3)^(m&7))<<4) + ((k&7)<<1));
}
__device__ __forceinline__ uint32_t laddrX(int m, int k) {
  return LDS_X + (uint32_t)(m*128) + (uint32_t)(((((k>>3)&7)^(m&7))<<4) + ((k&7)<<1));
}
struct __attribute__((aligned(8))) H4 { _Float16 h[4]; };

__device__ __forceinline__ float xenc_val(int j, float x0, float x1, float x2) {
  if (j >= 63) return 0.f;
  if (j < 3) return j==0?x0:(j==1?x1:x2);
  int q = j-3, lf = q/6, r = q%6, ci = r%3;
  float xc = (ci==0)?x0:((ci==1)?x1:x2);
  float arg = xc * (float)(1<<lf);
  return (r<3) ? sinf(arg) : cosf(arg);
}
__device__ __forceinline__ float denc_val(int c, float u0, float u1, float u2) {
  if (c >= 27) return 0.f;
  if (c < 3) return c==0?u0:(c==1?u1:u2);
  int q = c-3, lf = q/6, r = q%6, ci = r%3;
  float uc = (ci==0)?u0:((ci==1)?u1:u2);
  float arg = uc * (float)(1<<lf);
  return (r<3) ? sinf(arg) : cosf(arg);
}

// 4 waves, wave w = n-slice: frags [w*NF, w*NF+NF), rows 0..63 (MF=4).
// Weight ring: depth DW, lead LEAD=DW-1. XSTART: 0 => input entirely bufX;
// 100000 => entirely inb; else k>=XSTART reads bufX col k-XSTART.
// MODE 0: write smem outb (opt RELU, packed f16). MODE 1: head — n0<256 -> feat
// to outb (packed), else sem/sigma to global (f32 bias).
template<int KT, int NF, int MODE, bool RELU, int XSTART>
__device__ __forceinline__ void gemm(uint8_t* smem, uint32_t inb, uint32_t outb,
    const _Float16* __restrict__ WT, int fbase,
    const float* __restrict__ biasptr, const _Float16* __restrict__ biasHptr,
    int p0, float* __restrict__ sigmaws, _Float16* __restrict__ semws)
{
  constexpr int MF = 4;
  const int t = threadIdx.x;
  const int l = t & 63, w = t >> 6;
  const int lr = l & 15, lg = l >> 4;
  const int wn = w & 3;
  constexpr int DW   = (KT <= 3) ? KT : ((NF > 4) ? 3 : 4);
  constexpr int LEAD = (KT <= 3) ? KT : DW - 1;
  f32x4 acc[NF][MF];
#pragma unroll
  for (int i = 0; i < NF; ++i)
#pragma unroll
    for (int j = 0; j < MF; ++j) acc[i][j] = (f32x4){0.f,0.f,0.f,0.f};
  const _Float16* wb = WT + (size_t)((fbase + wn*NF)*KT)*512 + (size_t)l*8;
  half8 av[DW][NF];
  half8 bv[2][MF];
  auto baddr = [&](int row, int kt)->uint32_t {
    const int kk = kt*32 + lg*8;
    if (XSTART == 0) return laddrX(row, kk);
    if (XSTART < 100000 && kt*32 >= XSTART) return laddrX(row, kk - XSTART);
    return laddr(inb, row, kk);
  };
  // prologue: weights kt=0..LEAD-1 into slots 0..LEAD-1, activations kt=0
#pragma unroll
  for (int d = 0; d < LEAD && d < KT; ++d)
#pragma unroll
    for (int nf = 0; nf < NF; ++nf)
      av[d][nf] = *(const half8*)(wb + (size_t)(nf*KT + d)*512);
#pragma unroll
  for (int mf = 0; mf < MF; ++mf)
    bv[0][mf] = *(const half8*)(smem + baddr(mf*16 + lr, 0));
#pragma unroll
  for (int kt = 0; kt < KT; ++kt) {
    // issue future loads BEFORE the MFMA cluster, then pin.
    if (kt + 1 < KT) {
#pragma unroll
      for (int mf = 0; mf < MF; ++mf)
        bv[(kt+1)&1][mf] = *(const half8*)(smem + baddr(mf*16 + lr, kt+1));
    }
    if (kt + LEAD < KT) {
#pragma unroll
      for (int nf = 0; nf < NF; ++nf)
        av[(kt+LEAD)%DW][nf] = *(const half8*)(wb + (size_t)(nf*KT + kt + LEAD)*512);
    }
    __builtin_amdgcn_sched_barrier(0);
    __builtin_amdgcn_s_setprio(1);
#pragma unroll
    for (int nf = 0; nf < NF; ++nf)
#pragma unroll
      for (int mf = 0; mf < MF; ++mf)
        acc[nf][mf] = __builtin_amdgcn_mfma_f32_16x16x32_f16(av[kt%DW][nf], bv[kt&1][mf], acc[nf][mf], 0, 0, 0);
    __builtin_amdgcn_s_setprio(0);
    __builtin_amdgcn_sched_barrier(0);
  }
#pragma unroll
  for (int nf = 0; nf < NF; ++nf) {
    const int n0 = (wn*NF + nf)*16;
    const int nb = n0 + lg*4;
    if (MODE == 0 || n0 < 256) {
      const half2v* bh = (const half2v*)(biasHptr + nb);
      const half2v b0 = bh[0], b1 = bh[1];
#pragma unroll
      for (int mf = 0; mf < MF; ++mf) {
        const int m = mf*16 + lr;
        const f32x4 v = acc[nf][mf];
        half2v h0 = __builtin_amdgcn_cvt_pkrtz(v[0], v[1]) + b0;
        half2v h1 = __builtin_amdgcn_cvt_pkrtz(v[2], v[3]) + b1;
        if (RELU) {
          h0 = __builtin_elementwise_max(h0, (half2v)(__fp16)0);
          h1 = __builtin_elementwise_max(h1, (half2v)(__fp16)0);
        }
        H4 hh; *(half2v*)&hh.h[0] = h0; *(half2v*)&hh.h[2] = h1;
        *(H4*)(smem + laddr(outb, m, nb)) = hh;
      }
    } else {
      const int cb = nb - 256;                  // sem/sigma col offset (0..63)
      const f32x4 bvv = *(const f32x4*)(biasptr + nb);
#pragma unroll
      for (int mf = 0; mf < MF; ++mf) {
        const int m = mf*16 + lr;
        const int pp = p0 + m;
        f32x4 v = acc[nf][mf] + bvv;
        if (cb <= 44) {                         // 4 sem cols, 8B-aligned store
          H4 hh;
#pragma unroll
          for (int r = 0; r < 4; ++r) hh.h[r] = (_Float16)v[r];
          *(H4*)(semws + (size_t)pp*SEMSTR + cb) = hh;
        } else if (cb == 48) {                  // sem 48,49 + sigma (n=306)
          semws[(size_t)pp*SEMSTR + 48] = (_Float16)v[0];
          semws[(size_t)pp*SEMSTR + 49] = (_Float16)v[1];
          sigmaws[pp] = v[2];
        }
      }
    }
  }
}

__device__ __forceinline__ void gemm_rgb2(uint8_t* smem, uint32_t inb,
    const _Float16* __restrict__ WT, const float* __restrict__ bias,
    int p0, float* __restrict__ rgbws)
{
  const int t = threadIdx.x;
  const int l = t & 63, w = t >> 6;
  const int lr = l & 15, lg = l >> 4;
  const int m0 = w*16;
  f32x4 acc = (f32x4){0.f,0.f,0.f,0.f};
#pragma unroll
  for (int kt = 0; kt < 4; ++kt) {
    const int kk = kt*32 + lg*8;
    half8 a = *(const half8*)(WT + (size_t)kt*512 + (size_t)l*8);
    half8 b = *(const half8*)(smem + laddr(inb, m0 + lr, kk));
    acc = __builtin_amdgcn_mfma_f32_16x16x32_f16(a, b, acc, 0, 0, 0);
  }
  const int pp = p0 + m0 + lr;
#pragma unroll
  for (int r = 0; r < 4; ++r) {
    const int n = lg*4 + r;
    if (n < 3) rgbws[(size_t)pp*3 + n] = (float)acc[r] + bias[n];
  }
}

__global__ __launch_bounds__(256,2) void mlp_kernel(
    const float* __restrict__ rays, const float* __restrict__ zbuf,
    const float* __restrict__ scaleb, const _Float16* __restrict__ wt,
    const float* __restrict__ bias, const _Float16* __restrict__ biasH,
    float* __restrict__ sigmaws, float* __restrict__ rgbws,
    _Float16* __restrict__ semws)
{
  extern __shared__ uint8_t smem[];
  const int p0 = blockIdx.x*64;
  const int t = threadIdx.x;
  const int m = t & 63, g = t >> 6;
  const int p = p0 + m;
  const int ray = p / SAMP;
  const float sc = scaleb[ray];
  const float z  = zbuf[p];
  const float ox = rays[ray*6+0], oy = rays[ray*6+1], oz = rays[ray*6+2];
  const float dx = rays[ray*6+3], dy = rays[ray*6+4], dz = rays[ray*6+5];
  const float x0 = (ox + dx*z/sc)/200.f;
  const float x1 = (oy + dy*z/sc)/200.f;
  const float x2 = (oz + dz*z/sc)/200.f;
  const float u0 = dx/sc, u1 = dy/sc, u2 = dz/sc;
  // x_enc -> bufX: each thread row m, cols g*16..g*16+15 (two 16B writes)
  {
    union { _Float16 hv[8]; half8 v; } u8;
#pragma unroll
    for (int hf = 0; hf < 2; ++hf) {
      const int j0 = g*16 + hf*8;
#pragma unroll
      for (int jj = 0; jj < 8; ++jj) u8.hv[jj] = (_Float16)xenc_val(j0+jj, x0, x1, x2);
      *(half8*)(smem + laddrX(m, j0)) = u8.v;
    }
  }
  __syncthreads();
  gemm<2 ,4,0,true ,0     >(smem, LDS_X, LDS_A, wt+WT0_OFF,         0, bias+0,    biasH+0,    p0, sigmaws, semws); __syncthreads();
  gemm<8 ,4,0,true ,100000>(smem, LDS_A, LDS_B, wt+WTH_OFF+0*65536, 0, bias+256,  biasH+256,  p0, sigmaws, semws); __syncthreads();
  gemm<8 ,4,0,true ,100000>(smem, LDS_B, LDS_A, wt+WTH_OFF+1*65536, 0, bias+512,  biasH+512,  p0, sigmaws, semws); __syncthreads();
  gemm<8 ,4,0,true ,100000>(smem, LDS_A, LDS_B, wt+WTH_OFF+2*65536, 0, bias+768,  biasH+768,  p0, sigmaws, semws); __syncthreads();
  gemm<10,4,0,true ,256   >(smem, LDS_B, LDS_A, wt+WTS_OFF,         0, bias+1024, biasH+1024, p0, sigmaws, semws); __syncthreads();
  // overwrite bufX cols 0..31 with d_enc (x_enc dead after skip layer)
  {
    union { _Float16 hv[8]; half8 v; } u8;
    const int c0 = g*8;
#pragma unroll
    for (int cc = 0; cc < 8; ++cc) u8.hv[cc] = (_Float16)denc_val(c0+cc, u0, u1, u2);
    *(half8*)(smem + laddrX(m, c0)) = u8.v;
  }
  gemm<8 ,4,0,true ,100000>(smem, LDS_A, LDS_B, wt+WTH_OFF+3*65536, 0, bias+1280, biasH+1280, p0, sigmaws, semws); __syncthreads();
  gemm<8 ,4,0,true ,100000>(smem, LDS_B, LDS_A, wt+WTH_OFF+4*65536, 0, bias+1536, biasH+1536, p0, sigmaws, semws); __syncthreads();
  gemm<8 ,4,0,true ,100000>(smem, LDS_A, LDS_B, wt+WTH_OFF+5*65536, 0, bias+1792, biasH+1792, p0, sigmaws, semws); __syncthreads();
  // head: 320 cols in one pass (feat -> bufA, sem/sigma -> ws)
  gemm<8 ,5,1,false,100000>(smem, LDS_B, LDS_A, wt+WTHD_OFF,        0, bias+2048, biasH+2048, p0, sigmaws, semws); __syncthreads();
  gemm<9 ,2,0,true ,256   >(smem, LDS_A, LDS_B, wt+WTR1_OFF,        0, bias+2368, biasH+2368, p0, sigmaws, semws); __syncthreads();
  gemm_rgb2(smem, LDS_B, wt+WTR2_OFF, bias+2496, p0, rgbws);
}

// ============================================================== compositing
__global__ __launch_bounds__(128) void comp_kernel(
    const float* __restrict__ inter, const float* __restrict__ zbuf,
    const float* __restrict__ scaleb, const float* __restrict__ sigmaws,
    const float* __restrict__ rgbws, const _Float16* __restrict__ semws,
    float* __restrict__ out)
{
  __shared__ float zt[84], alpha[84], wgt[84];
  const int ray = blockIdx.x, t = threadIdx.x;
  const float sc = scaleb[ray];
  const float* bx = inter + (size_t)ray*40;
  if (t < 84) zt[t] = zbuf[(size_t)ray*84 + t] / sc;
  __syncthreads();
  if (t < 84) {
    const float z = zbuf[(size_t)ray*84 + t];
    bool inside = false, bound = false;
    for (int b = 0; b < 10; ++b) {
      const float nr = bx[b*4], fr = bx[b*4+1];
      inside = inside || (z > nr && z < fr);
      const float d1 = z - fr, d2 = nr - z;
      bound = bound || (d1 > 0.f && d1 < 1e-3f) || (d2 > 0.f && d2 < 1e-3f);
    }
    float sg = sigmaws[(size_t)ray*84 + t];
    const bool bbox = (z < 200.f) && !inside;
    if (bbox || bound) sg = 0.f;
    sg = fmaxf(sg, 0.f);
    const float dist = (t < 83) ? (zt[t+1] - zt[t])*sc : 1e10f*sc;
    alpha[t] = 1.f - expf(-sg*dist);
  }
  __syncthreads();
  if (t == 0) {
    float T = 1.f;
    for (int s = 0; s < 84; ++s) { wgt[s] = alpha[s]*T; T *= (1.f - alpha[s] + 1e-10f); }
  }
  __syncthreads();
  if (t < 55) {
    float a = 0.f;
    const size_t base = (size_t)ray*84;
    if (t < 50) {
      for (int s = 0; s < 84; ++s) a += wgt[s]*(float)semws[(base+s)*SEMSTR + t];
      out[(size_t)ray*55 + 5 + t] = a;
    } else if (t < 53) {
      const int c = t - 50;
      for (int s = 0; s < 84; ++s) { const float r = rgbws[(base+s)*3 + c]; a += wgt[s]/(1.f + expf(-r)); }
      out[(size_t)ray*55 + c] = a;
    } else if (t == 53) {
      for (int s = 0; s < 84; ++s) a += wgt[s]*zt[s];
      out[(size_t)ray*55 + 3] = a;
    } else {
      for (int s = 0; s < 84; ++s) a += wgt[s];
      out[(size_t)ray*55 + 4] = a;
    }
  }
}

// ============================================================== launch
extern "C" void kernel_launch(void* const* d_in, const int* in_sizes, int n_in,
                              void* d_out, int out_size, void* d_ws, size_t ws_size,
                              hipStream_t stream) {
  const float* rays   = (const float*)d_in[0];
  const float* inter  = (const float*)d_in[1];
  const float* noise  = (const float*)d_in[2];
  const float* w_in   = (const float*)d_in[3];
  const float* b_in   = (const float*)d_in[4];
  const float* w_h    = (const float*)d_in[5];
  const float* b_h    = (const float*)d_in[6];
  const float* w_skip = (const float*)d_in[7];
  const float* b_skip = (const float*)d_in[8];
  const float* w_sig  = (const float*)d_in[9];
  const float* b_sig  = (const float*)d_in[10];
  const float* w_feat = (const float*)d_in[11];
  const float* b_feat = (const float*)d_in[12];
  const float* w_rgb1 = (const float*)d_in[13];
  const float* b_rgb1 = (const float*)d_in[14];
  const float* w_rgb2 = (const float*)d_in[15];
  const float* b_rgb2 = (const float*)d_in[16];
  const float* w_sem  = (const float*)d_in[17];
  const float* b_sem  = (const float*)d_in[18];

  uint8_t* ws = (uint8_t*)d_ws;
  _Float16* wt    = (_Float16*)(ws + OFF_WT);
  float* bias     = (float*)(ws + OFF_BIAS);
  _Float16* biasH = (_Float16*)(ws + OFF_BIASH);
  float* zbuf     = (float*)(ws + OFF_Z);
  float* scaleb   = (float*)(ws + OFF_SCALE);
  float* sigmaws  = (float*)(ws + OFF_SIGMA);
  float* rgbws    = (float*)(ws + OFF_RGB);
  _Float16* semws = (_Float16*)(ws + OFF_SEM);

  prep_kernel<<<dim3((WT_TOTAL + NBIAS + 255)/256), dim3(256), 0, stream>>>(
      w_in, w_h, w_skip, w_sig, w_feat, w_rgb1, w_rgb2, w_sem,
      b_in, b_h, b_skip, b_sig, b_feat, b_rgb1, b_rgb2, b_sem, wt, bias, biasH);
  sample_kernel<<<dim3(NRAYS), dim3(256), 0, stream>>>(rays, inter, noise, zbuf, scaleb);
  mlp_kernel<<<dim3(NPTS/64), dim3(256), LDS_TOTAL, stream>>>(
      rays, zbuf, scaleb, wt, bias, biasH, sigmaws, rgbws, semws);
  comp_kernel<<<dim3(NRAYS), dim3(128), 0, stream>>>(
      inter, zbuf, scaleb, sigmaws, rgbws, semws, (float*)d_out);
}

// Round 14
// 265.396 us; speedup vs baseline: 1.1025x; 1.0104x over previous
//
#include <hip/hip_runtime.h>

typedef _Float16 half8 __attribute__((ext_vector_type(8)));
typedef __fp16  half2v __attribute__((ext_vector_type(2)));
typedef float f32x4 __attribute__((ext_vector_type(4)));

#define NRAYS 2048
#define SAMP 84
#define NPTS (NRAYS*SAMP)   // 172032
#define SEMSTR 52           // padded sem row stride (halves)

// ---- half-element offsets inside the weight region (fragment-packed) ----
// layout per region: [frag F][kt][lane l][h 0..7] ; n = F*16 + (l&15), k = kt*32 + (l>>4)*8 + h
#define WT0_OFF   0         // 16 frags x KT2
#define WTH_OFF   16384     // 6 x (16 frags x KT8)
#define WTS_OFF   409600    // 16 frags x KT10
#define WTHD_OFF  491520    // 20 frags x KT8
#define WTR1_OFF  573440    // 8 frags x KT9
#define WTR2_OFF  610304    // 1 frag x KT4
#define WT_TOTAL  612352
#define NBIAS     2512
#define PREP_BLOCKS ((WT_TOTAL + NBIAS + 255)/256)   // 2402

// ---- ws byte offsets ----
#define OFF_WT    ((size_t)0)
#define OFF_BIAS  ((size_t)1224704)                 // WT_TOTAL*2
#define OFF_BIASH ((size_t)1234752)                 // OFF_BIAS + NBIAS*4
#define OFF_Z     ((size_t)1239808)                 // OFF_BIASH + NBIAS*2 (padded)
#define OFF_SCALE (OFF_Z + (size_t)NPTS*4)
#define OFF_SIGMA (OFF_SCALE + (size_t)NRAYS*4)
#define OFF_RGB   (OFF_SIGMA + (size_t)NPTS*4)
#define OFF_SEM   (OFF_RGB + (size_t)NPTS*12)

// ============================================================== setup (prep + sample fused)
__global__ __launch_bounds__(256) void setup_kernel(
    const float* __restrict__ w_in,  const float* __restrict__ w_h,
    const float* __restrict__ w_skip,const float* __restrict__ w_sigma,
    const float* __restrict__ w_feat,const float* __restrict__ w_rgb1,
    const float* __restrict__ w_rgb2,const float* __restrict__ w_sem,
    const float* __restrict__ b_in,  const float* __restrict__ b_h,
    const float* __restrict__ b_skip,const float* __restrict__ b_sigma,
    const float* __restrict__ b_feat,const float* __restrict__ b_rgb1,
    const float* __restrict__ b_rgb2,const float* __restrict__ b_sem,
    const float* __restrict__ rays,  const float* __restrict__ inter,
    const float* __restrict__ noise,
    _Float16* __restrict__ wt, float* __restrict__ bias,
    _Float16* __restrict__ biasH, float* __restrict__ zbuf,
    float* __restrict__ scaleb)
{
  if (blockIdx.x < PREP_BLOCKS) {
    int idx = blockIdx.x*256 + threadIdx.x;
    if (idx < WT_TOTAL) {
      float v; int n, k, l, h, q;
      if (idx < WTH_OFF) {                 // L0: 16 frags, KT=2
        int r = idx; int F = r >> 10; int rem = r & 1023; int kt = rem >> 9; q = rem & 511;
        l = q >> 3; h = q & 7;
        n = F*16 + (l&15); k = kt*32 + (l>>4)*8 + h;
        v = (k < 63) ? w_in[k*256 + n] : 0.f;
      } else if (idx < WTS_OFF) {          // hidden: 6 x (16 frags x KT8)
        int r = idx - WTH_OFF; int i = r >> 16; int r2 = r & 65535;
        int F = r2 >> 12; int kt = (r2 >> 9) & 7; q = r2 & 511;
        l = q >> 3; h = q & 7;
        n = F*16 + (l&15); k = kt*32 + (l>>4)*8 + h;
        v = w_h[(i<<16) + (k<<8) + n];
      } else if (idx < WTHD_OFF) {         // skip: 16 frags x KT10
        int r = idx - WTS_OFF; int F = r / 5120; int rem = r % 5120; int kt = rem >> 9; q = rem & 511;
        l = q >> 3; h = q & 7;
        n = F*16 + (l&15); k = kt*32 + (l>>4)*8 + h;
        v = (k < 319) ? w_skip[k*256 + n] : 0.f;
      } else if (idx < WTR1_OFF) {         // head: 20 frags x KT8
        int r = idx - WTHD_OFF; int F = r >> 12; int kt = (r >> 9) & 7; q = r & 511;
        l = q >> 3; h = q & 7;
        n = F*16 + (l&15); k = kt*32 + (l>>4)*8 + h;
        v = (n < 256) ? w_feat[(k<<8) + n]
          : (n < 306) ? w_sem[k*50 + (n-256)]
          : (n == 306)? w_sigma[k] : 0.f;
      } else if (idx < WTR2_OFF) {         // rgb1: 8 frags x KT9
        int r = idx - WTR1_OFF; int F = r / 4608; int rem = r % 4608; int kt = rem >> 9; q = rem & 511;
        l = q >> 3; h = q & 7;
        n = F*16 + (l&15); k = kt*32 + (l>>4)*8 + h;
        v = (k < 283) ? w_rgb1[k*128 + n] : 0.f;
      } else {                             // rgb2: 1 frag x KT4
        int r = idx - WTR2_OFF; int kt = r >> 9; q = r & 511;
        l = q >> 3; h = q & 7;
        n = (l&15); k = kt*32 + (l>>4)*8 + h;
        v = (n < 3) ? w_rgb2[k*3 + n] : 0.f;
      }
      wt[idx] = (_Float16)v;
    } else if (idx < WT_TOTAL + NBIAS) {
      int j = idx - WT_TOTAL; float v;
      if (j < 2048) {
        int i = j >> 8, c = j & 255;
        v = (i==0) ? b_in[c] : (i<4) ? b_h[(i-1)*256+c]
          : (i==4) ? b_skip[c] : b_h[(i-2)*256+c];
      } else if (j < 2368) {
        int c = j - 2048;
        v = (c<256) ? b_feat[c] : (c<306) ? b_sem[c-256]
          : (c==306) ? b_sigma[0] : 0.f;
      } else if (j < 2496) v = b_rgb1[j-2368];
      else { int c = j-2496; v = (c<3) ? b_rgb2[c] : 0.f; }
      bias[j] = v;
      biasH[j] = (_Float16)v;
    }
    return;
  }
  // ---------------- sample path ----------------
  __shared__ float sv[240], ss[240], z2[84];
  const int ray = blockIdx.x - PREP_BLOCKS, t = threadIdx.x;
  const float* bx = inter + (size_t)ray*40;
  if (t < 240) {
    int b = t/24, j = t%24;
    float nr = bx[b*4], fr = bx[b*4+1];
    float tj = (j==23) ? 1.f : (float)j * (1.f/23.f);
    sv[t] = nr + (fr-nr)*tj;
  }
  __syncthreads();
  if (t < 240) {
    float v = sv[t]; int r = 0;
    for (int i = 0; i < 240; ++i) { float vi = sv[i]; r += (vi < v) || (vi == v && i < t); }
    ss[r] = v;
  }
  __syncthreads();
  if (t < 64) {
    float z;
    if (t == 63) z = ss[239];
    else { int num = t*239; int k = num/63; float f = (float)(num - k*63)*(1.f/63.f);
           z = ss[k] + f*(ss[k+1]-ss[k]); }
    z2[t] = z;
  } else if (t < 84) {
    int b = t - 64;
    z2[t] = (b < 10) ? (bx[b*4] - 1e-5f) : (bx[(b-10)*4+1] + 1e-5f);
  }
  __syncthreads();
  if (t < 84) { float z = z2[t]; if (z < 0.f) z = 200.f + 20.f*noise[(size_t)ray*84 + t]; z2[t] = z; }
  __syncthreads();
  if (t < 84) {
    float v = z2[t]; int r = 0;
    for (int i = 0; i < 84; ++i) { float vi = z2[i]; r += (vi < v) || (vi == v && i < t); }
    zbuf[(size_t)ray*84 + r] = v;
  }
  if (t == 0) {
    float dx = rays[ray*6+3], dy = rays[ray*6+4], dz = rays[ray*6+5];
    scaleb[ray] = sqrtf(dx*dx + dy*dy + dz*dz);
  }
}

// ============================================================== MLP
// 64 pts/block, 256 threads (4 waves, pure n-split). Per wave: ALL 64 rows x NF*16 cols.
// LDS: bufA (64x256 f16, 32KB) @0, bufB @32768, bufX (64x64 f16, 8KB) @65536. 72KB -> 2 blocks/CU.
#define LDS_A 0u
#define LDS_B 32768u
#define LDS_X 65536u
#define LDS_TOTAL 73728

__device__ __forceinline__ uint32_t laddr(uint32_t base, int m, int k) {
  return base + (uint32_t)(m*512) + (uint32_t)((((k>>3)^(m&7))<<4) + ((k&7)<<1));
}
__device__ __forceinline__ uint32_t laddrX(int m, int k) {
  return LDS_X + (uint32_t)(m*128) + (uint32_t)(((((k>>3)&7)^(m&7))<<4) + ((k&7)<<1));
}
struct __attribute__((aligned(8))) H4 { _Float16 h[4]; };

__device__ __forceinline__ float xenc_val(int j, float x0, float x1, float x2) {
  if (j >= 63) return 0.f;
  if (j < 3) return j==0?x0:(j==1?x1:x2);
  int q = j-3, lf = q/6, r = q%6, ci = r%3;
  float xc = (ci==0)?x0:((ci==1)?x1:x2);
  float arg = xc * (float)(1<<lf);
  return (r<3) ? sinf(arg) : cosf(arg);
}
__device__ __forceinline__ float denc_val(int c, float u0, float u1, float u2) {
  if (c >= 27) return 0.f;
  if (c < 3) return c==0?u0:(c==1?u1:u2);
  int q = c-3, lf = q/6, r = q%6, ci = r%3;
  float uc = (ci==0)?u0:((ci==1)?u1:u2);
  float arg = uc * (float)(1<<lf);
  return (r<3) ? sinf(arg) : cosf(arg);
}

// 4 waves, wave w = n-slice: frags [w*NF, w*NF+NF), rows 0..63 (MF=4).
// Weight ring: depth DW, lead LEAD=DW-1. XSTART: 0 => input entirely bufX;
// 100000 => entirely inb; else k>=XSTART reads bufX col k-XSTART.
// MODE 0: write smem outb (opt RELU, packed f16). MODE 1: head — n0<256 -> feat
// to outb (packed), else sem/sigma to global (f32 bias).
template<int KT, int NF, int MODE, bool RELU, int XSTART>
__device__ __forceinline__ void gemm(uint8_t* smem, uint32_t inb, uint32_t outb,
    const _Float16* __restrict__ WT, int fbase,
    const float* __restrict__ biasptr, const _Float16* __restrict__ biasHptr,
    int p0, float* __restrict__ sigmaws, _Float16* __restrict__ semws)
{
  constexpr int MF = 4;
  const int t = threadIdx.x;
  const int l = t & 63, w = t >> 6;
  const int lr = l & 15, lg = l >> 4;
  const int wn = w & 3;
  constexpr int DW   = (KT <= 3) ? KT : ((NF > 4) ? 3 : 4);
  constexpr int LEAD = (KT <= 3) ? KT : DW - 1;
  f32x4 acc[NF][MF];
#pragma unroll
  for (int i = 0; i < NF; ++i)
#pragma unroll
    for (int j = 0; j < MF; ++j) acc[i][j] = (f32x4){0.f,0.f,0.f,0.f};
  const _Float16* wb = WT + (size_t)((fbase + wn*NF)*KT)*512 + (size_t)l*8;
  half8 av[DW][NF];
  half8 bv[2][MF];
  auto baddr = [&](int row, int kt)->uint32_t {
    const int kk = kt*32 + lg*8;
    if (XSTART == 0) return laddrX(row, kk);
    if (XSTART < 100000 && kt*32 >= XSTART) return laddrX(row, kk - XSTART);
    return laddr(inb, row, kk);
  };
  // prologue: weights kt=0..LEAD-1 into slots 0..LEAD-1, activations kt=0
#pragma unroll
  for (int d = 0; d < LEAD && d < KT; ++d)
#pragma unroll
    for (int nf = 0; nf < NF; ++nf)
      av[d][nf] = *(const half8*)(wb + (size_t)(nf*KT + d)*512);
#pragma unroll
  for (int mf = 0; mf < MF; ++mf)
    bv[0][mf] = *(const half8*)(smem + baddr(mf*16 + lr, 0));
#pragma unroll
  for (int kt = 0; kt < KT; ++kt) {
    // issue future loads BEFORE the MFMA cluster, then pin.
    if (kt + 1 < KT) {
#pragma unroll
      for (int mf = 0; mf < MF; ++mf)
        bv[(kt+1)&1][mf] = *(const half8*)(smem + baddr(mf*16 + lr, kt+1));
    }
    if (kt + LEAD < KT) {
#pragma unroll
      for (int nf = 0; nf < NF; ++nf)
        av[(kt+LEAD)%DW][nf] = *(const half8*)(wb + (size_t)(nf*KT + kt + LEAD)*512);
    }
    __builtin_amdgcn_sched_barrier(0);
    __builtin_amdgcn_s_setprio(1);
#pragma unroll
    for (int nf = 0; nf < NF; ++nf)
#pragma unroll
      for (int mf = 0; mf < MF; ++mf)
        acc[nf][mf] = __builtin_amdgcn_mfma_f32_16x16x32_f16(av[kt%DW][nf], bv[kt&1][mf], acc[nf][mf], 0, 0, 0);
    __builtin_amdgcn_s_setprio(0);
    __builtin_amdgcn_sched_barrier(0);
  }
#pragma unroll
  for (int nf = 0; nf < NF; ++nf) {
    const int n0 = (wn*NF + nf)*16;
    const int nb = n0 + lg*4;
    if (MODE == 0 || n0 < 256) {
      const half2v* bh = (const half2v*)(biasHptr + nb);
      const half2v b0 = bh[0], b1 = bh[1];
#pragma unroll
      for (int mf = 0; mf < MF; ++mf) {
        const int m = mf*16 + lr;
        const f32x4 v = acc[nf][mf];
        half2v h0 = __builtin_amdgcn_cvt_pkrtz(v[0], v[1]) + b0;
        half2v h1 = __builtin_amdgcn_cvt_pkrtz(v[2], v[3]) + b1;
        if (RELU) {
          h0 = __builtin_elementwise_max(h0, (half2v)(__fp16)0);
          h1 = __builtin_elementwise_max(h1, (half2v)(__fp16)0);
        }
        H4 hh; *(half2v*)&hh.h[0] = h0; *(half2v*)&hh.h[2] = h1;
        *(H4*)(smem + laddr(outb, m, nb)) = hh;
      }
    } else {
      const int cb = nb - 256;                  // sem/sigma col offset (0..63)
      const f32x4 bvv = *(const f32x4*)(biasptr + nb);
#pragma unroll
      for (int mf = 0; mf < MF; ++mf) {
        const int m = mf*16 + lr;
        const int pp = p0 + m;
        f32x4 v = acc[nf][mf] + bvv;
        if (cb <= 44) {                         // 4 sem cols, 8B-aligned store
          H4 hh;
#pragma unroll
          for (int r = 0; r < 4; ++r) hh.h[r] = (_Float16)v[r];
          *(H4*)(semws + (size_t)pp*SEMSTR + cb) = hh;
        } else if (cb == 48) {                  // sem 48,49 + sigma (n=306)
          semws[(size_t)pp*SEMSTR + 48] = (_Float16)v[0];
          semws[(size_t)pp*SEMSTR + 49] = (_Float16)v[1];
          sigmaws[pp] = v[2];
        }
      }
    }
  }
}

__device__ __forceinline__ void gemm_rgb2(uint8_t* smem, uint32_t inb,
    const _Float16* __restrict__ WT, const float* __restrict__ bias,
    int p0, float* __restrict__ rgbws)
{
  const int t = threadIdx.x;
  const int l = t & 63, w = t >> 6;
  const int lr = l & 15, lg = l >> 4;
  const int m0 = w*16;
  f32x4 acc = (f32x4){0.f,0.f,0.f,0.f};
#pragma unroll
  for (int kt = 0; kt < 4; ++kt) {
    const int kk = kt*32 + lg*8;
    half8 a = *(const half8*)(WT + (size_t)kt*512 + (size_t)l*8);
    half8 b = *(const half8*)(smem + laddr(inb, m0 + lr, kk));
    acc = __builtin_amdgcn_mfma_f32_16x16x32_f16(a, b, acc, 0, 0, 0);
  }
  const int pp = p0 + m0 + lr;
#pragma unroll
  for (int r = 0; r < 4; ++r) {
    const int n = lg*4 + r;
    if (n < 3) rgbws[(size_t)pp*3 + n] = (float)acc[r] + bias[n];
  }
}

__global__ __launch_bounds__(256,2) void mlp_kernel(
    const float* __restrict__ rays, const float* __restrict__ zbuf,
    const float* __restrict__ scaleb, const _Float16* __restrict__ wt,
    const float* __restrict__ bias, const _Float16* __restrict__ biasH,
    float* __restrict__ sigmaws, float* __restrict__ rgbws,
    _Float16* __restrict__ semws)
{
  extern __shared__ uint8_t smem[];
  const int p0 = blockIdx.x*64;
  const int t = threadIdx.x;
  const int m = t & 63, g = t >> 6;
  const int p = p0 + m;
  const int ray = p / SAMP;
  const float sc = scaleb[ray];
  const float z  = zbuf[p];
  const float ox = rays[ray*6+0], oy = rays[ray*6+1], oz = rays[ray*6+2];
  const float dx = rays[ray*6+3], dy = rays[ray*6+4], dz = rays[ray*6+5];
  const float x0 = (ox + dx*z/sc)/200.f;
  const float x1 = (oy + dy*z/sc)/200.f;
  const float x2 = (oz + dz*z/sc)/200.f;
  const float u0 = dx/sc, u1 = dy/sc, u2 = dz/sc;
  // x_enc -> bufX: each thread row m, cols g*16..g*16+15 (two 16B writes)
  {
    union { _Float16 hv[8]; half8 v; } u8;
#pragma unroll
    for (int hf = 0; hf < 2; ++hf) {
      const int j0 = g*16 + hf*8;
#pragma unroll
      for (int jj = 0; jj < 8; ++jj) u8.hv[jj] = (_Float16)xenc_val(j0+jj, x0, x1, x2);
      *(half8*)(smem + laddrX(m, j0)) = u8.v;
    }
  }
  __syncthreads();
  gemm<2 ,4,0,true ,0     >(smem, LDS_X, LDS_A, wt+WT0_OFF,         0, bias+0,    biasH+0,    p0, sigmaws, semws); __syncthreads();
  gemm<8 ,4,0,true ,100000>(smem, LDS_A, LDS_B, wt+WTH_OFF+0*65536, 0, bias+256,  biasH+256,  p0, sigmaws, semws); __syncthreads();
  gemm<8 ,4,0,true ,100000>(smem, LDS_B, LDS_A, wt+WTH_OFF+1*65536, 0, bias+512,  biasH+512,  p0, sigmaws, semws); __syncthreads();
  gemm<8 ,4,0,true ,100000>(smem, LDS_A, LDS_B, wt+WTH_OFF+2*65536, 0, bias+768,  biasH+768,  p0, sigmaws, semws); __syncthreads();
  gemm<10,4,0,true ,256   >(smem, LDS_B, LDS_A, wt+WTS_OFF,         0, bias+1024, biasH+1024, p0, sigmaws, semws); __syncthreads();
  // overwrite bufX cols 0..31 with d_enc (x_enc dead after skip layer)
  {
    union { _Float16 hv[8]; half8 v; } u8;
    const int c0 = g*8;
#pragma unroll
    for (int cc = 0; cc < 8; ++cc) u8.hv[cc] = (_Float16)denc_val(c0+cc, u0, u1, u2);
    *(half8*)(smem + laddrX(m, c0)) = u8.v;
  }
  gemm<8 ,4,0,true ,100000>(smem, LDS_A, LDS_B, wt+WTH_OFF+3*65536, 0, bias+1280, biasH+1280, p0, sigmaws, semws); __syncthreads();
  gemm<8 ,4,0,true ,100000>(smem, LDS_B, LDS_A, wt+WTH_OFF+4*65536, 0, bias+1536, biasH+1536, p0, sigmaws, semws); __syncthreads();
  gemm<8 ,4,0,true ,100000>(smem, LDS_A, LDS_B, wt+WTH_OFF+5*65536, 0, bias+1792, biasH+1792, p0, sigmaws, semws); __syncthreads();
  // head: 320 cols in one pass (feat -> bufA, sem/sigma -> ws)
  gemm<8 ,5,1,false,100000>(smem, LDS_B, LDS_A, wt+WTHD_OFF,        0, bias+2048, biasH+2048, p0, sigmaws, semws); __syncthreads();
  gemm<9 ,2,0,true ,256   >(smem, LDS_A, LDS_B, wt+WTR1_OFF,        0, bias+2368, biasH+2368, p0, sigmaws, semws); __syncthreads();
  gemm_rgb2(smem, LDS_B, wt+WTR2_OFF, bias+2496, p0, rgbws);
}

// ============================================================== compositing
// LDS-staged: per ray, coalesced bulk load of sem (8736B), rgb (1008B),
// sigma (336B), z (336B); reductions then read LDS only. Mask tests use the
// EXACT z from zbuf (zs[]) — z_bound samples sit 1e-5 from box boundaries, so
// any divide/multiply round-trip flips inside/bound classification.
__global__ __launch_bounds__(128) void comp_kernel(
    const float* __restrict__ inter, const float* __restrict__ zbuf,
    const float* __restrict__ scaleb, const float* __restrict__ sigmaws,
    const float* __restrict__ rgbws, const _Float16* __restrict__ semws,
    float* __restrict__ out)
{
  __shared__ _Float16 sems[84*SEMSTR];   // 8736 B
  __shared__ float srgb[84*3];
  __shared__ float ssig[84];
  __shared__ float zs[84], zt[84], alpha[84], wgt[84];
  const int ray = blockIdx.x, t = threadIdx.x;
  const float sc = scaleb[ray];
  const float* bx = inter + (size_t)ray*40;
  // bulk loads (contiguous per ray)
  {
    const half8* semp = (const half8*)(semws + (size_t)ray*84*SEMSTR); // 546 x 16B
    half8* semd = (half8*)sems;
    for (int i = t; i < 546; i += 128) semd[i] = semp[i];
    const float* rgbp = rgbws + (size_t)ray*84*3;                      // 252 floats
    for (int i = t; i < 252; i += 128) srgb[i] = rgbp[i];
    if (t < 84) {
      const float zexact = zbuf[(size_t)ray*84 + t];
      zs[t]   = zexact;
      zt[t]   = zexact / sc;
      ssig[t] = sigmaws[(size_t)ray*84 + t];
    }
  }
  __syncthreads();
  if (t < 84) {
    const float z = zs[t];                       // exact
    bool inside = false, bound = false;
    for (int b = 0; b < 10; ++b) {
      const float nr = bx[b*4], fr = bx[b*4+1];
      inside = inside || (z > nr && z < fr);
      const float d1 = z - fr, d2 = nr - z;
      bound = bound || (d1 > 0.f && d1 < 1e-3f) || (d2 > 0.f && d2 < 1e-3f);
    }
    float sg = ssig[t];
    const bool bbox = (z < 200.f) && !inside;
    if (bbox || bound) sg = 0.f;
    sg = fmaxf(sg, 0.f);
    const float dist = (t < 83) ? (zt[t+1] - zt[t])*sc : 1e10f*sc;
    alpha[t] = 1.f - expf(-sg*dist);
  }
  __syncthreads();
  if (t == 0) {
    float T = 1.f;
    for (int s = 0; s < 84; ++s) { wgt[s] = alpha[s]*T; T *= (1.f - alpha[s] + 1e-10f); }
  }
  __syncthreads();
  if (t < 55) {
    float a = 0.f;
    if (t < 50) {
      for (int s = 0; s < 84; ++s) a += wgt[s]*(float)sems[s*SEMSTR + t];
      out[(size_t)ray*55 + 5 + t] = a;
    } else if (t < 53) {
      const int c = t - 50;
      for (int s = 0; s < 84; ++s) { const float r = srgb[s*3 + c]; a += wgt[s]/(1.f + expf(-r)); }
      out[(size_t)ray*55 + c] = a;
    } else if (t == 53) {
      for (int s = 0; s < 84; ++s) a += wgt[s]*zt[s];
      out[(size_t)ray*55 + 3] = a;
    } else {
      for (int s = 0; s < 84; ++s) a += wgt[s];
      out[(size_t)ray*55 + 4] = a;
    }
  }
}

// ============================================================== launch
extern "C" void kernel_launch(void* const* d_in, const int* in_sizes, int n_in,
                              void* d_out, int out_size, void* d_ws, size_t ws_size,
                              hipStream_t stream) {
  const float* rays   = (const float*)d_in[0];
  const float* inter  = (const float*)d_in[1];
  const float* noise  = (const float*)d_in[2];
  const float* w_in   = (const float*)d_in[3];
  const float* b_in   = (const float*)d_in[4];
  const float* w_h    = (const float*)d_in[5];
  const float* b_h    = (const float*)d_in[6];
  const float* w_skip = (const float*)d_in[7];
  const float* b_skip = (const float*)d_in[8];
  const float* w_sig  = (const float*)d_in[9];
  const float* b_sig  = (const float*)d_in[10];
  const float* w_feat = (const float*)d_in[11];
  const float* b_feat = (const float*)d_in[12];
  const float* w_rgb1 = (const float*)d_in[13];
  const float* b_rgb1 = (const float*)d_in[14];
  const float* w_rgb2 = (const float*)d_in[15];
  const float* b_rgb2 = (const float*)d_in[16];
  const float* w_sem  = (const float*)d_in[17];
  const float* b_sem  = (const float*)d_in[18];

  uint8_t* ws = (uint8_t*)d_ws;
  _Float16* wt    = (_Float16*)(ws + OFF_WT);
  float* bias     = (float*)(ws + OFF_BIAS);
  _Float16* biasH = (_Float16*)(ws + OFF_BIASH);
  float* zbuf     = (float*)(ws + OFF_Z);
  float* scaleb   = (float*)(ws + OFF_SCALE);
  float* sigmaws  = (float*)(ws + OFF_SIGMA);
  float* rgbws    = (float*)(ws + OFF_RGB);
  _Float16* semws = (_Float16*)(ws + OFF_SEM);

  setup_kernel<<<dim3(PREP_BLOCKS + NRAYS), dim3(256), 0, stream>>>(
      w_in, w_h, w_skip, w_sig, w_feat, w_rgb1, w_rgb2, w_sem,
      b_in, b_h, b_skip, b_sig, b_feat, b_rgb1, b_rgb2, b_sem,
      rays, inter, noise, wt, bias, biasH, zbuf, scaleb);
  mlp_kernel<<<dim3(NPTS/64), dim3(256), LDS_TOTAL, stream>>>(
      rays, zbuf, scaleb, wt, bias, biasH, sigmaws, rgbws, semws);
  comp_kernel<<<dim3(NRAYS), dim3(128), 0, stream>>>(
      inter, zbuf, scaleb, sigmaws, rgbws, semws, (float*)d_out);
}